// Round 2
// baseline (1603.242 us; speedup 1.0000x reference)
//
#include <hip/hip_runtime.h>
#include <cstdint>
#include <cstddef>

// Problem constants (match reference)
#define HFEAT 128
#define FFEAT 256

// ---------------- degree kernels ----------------
__global__ void set_deg_kernel(float* __restrict__ deg, int n) {
    int i = blockIdx.x * blockDim.x + threadIdx.x;
    if (i < n) deg[i] = 1.0f;  // self-loop contributes 1 to every node
}

__global__ void count_deg_kernel(const int* __restrict__ dst, float* __restrict__ deg, int e) {
    int i = blockIdx.x * blockDim.x + threadIdx.x;
    if (i < e) atomicAdd(&deg[dst[i]], 1.0f);
}

__global__ void rsqrt_kernel(float* __restrict__ deg, int n) {
    int i = blockIdx.x * blockDim.x + threadIdx.x;
    if (i < n) deg[i] = rsqrtf(deg[i]);  // deg >= 1 always (self-loops)
}

// ---------------- GEMM: C = act(A[M,K] @ B[K,NCOL] + bias) ----------------
// block = 256 threads, 16 rows of A per block staged in LDS; B streamed via L2.
template<int K, int NCOL, int ACT>
__global__ __launch_bounds__(256) void gemm_kernel(
    const float* __restrict__ A, const float* __restrict__ B,
    const float* __restrict__ bias, float* __restrict__ C, int M) {
    constexpr int TM = 16;
    __shared__ float As[TM * K];
    const int row0 = blockIdx.x * TM;
    const int tid = threadIdx.x;
    // cooperative float4 load of the A tile
    for (int i = tid; i < (TM * K) / 4; i += 256) {
        int idx = i * 4;
        int r = idx / K, k = idx - r * K;
        int grow = row0 + r;
        float4 v = make_float4(0.f, 0.f, 0.f, 0.f);
        if (grow < M) v = *(const float4*)(A + (size_t)grow * K + k);
        *(float4*)(As + idx) = v;
    }
    __syncthreads();
    constexpr int RPT = (TM * NCOL) / 256;  // rows per thread
    const int c = tid % NCOL;
    const int rb = (tid / NCOL) * RPT;
    float acc[RPT];
#pragma unroll
    for (int r = 0; r < RPT; r++) acc[r] = 0.f;
    for (int k = 0; k < K; k++) {
        float bv = B[(size_t)k * NCOL + c];
#pragma unroll
        for (int r = 0; r < RPT; r++)
            acc[r] = fmaf(As[(rb + r) * K + k], bv, acc[r]);
    }
    float bb = bias ? bias[c] : 0.f;
#pragma unroll
    for (int r = 0; r < RPT; r++) {
        int grow = row0 + rb + r;
        if (grow >= M) continue;
        float v = acc[r] + bb;
        if (ACT == 1) v = v > 0.f ? v : 0.f;
        if (ACT == 2) v = 1.f / (1.f + __expf(-v));
        C[(size_t)grow * NCOL + c] = v;
    }
}

// ---------------- out init: self-loop term + bias ----------------
__global__ void init_out_kernel(const float* __restrict__ h, const float* __restrict__ dinv,
                                const float* __restrict__ bgcn, float* __restrict__ out, int n) {
    int idx = blockIdx.x * blockDim.x + threadIdx.x;  // n*32 items, float4 each
    if (idx >= n * 32) return;
    int i = idx >> 5;
    int c4 = (idx & 31) * 4;
    float di = dinv[i];
    float nn = di * di;
    float4 hv = *(const float4*)(h + (size_t)i * HFEAT + c4);
    float4 bb = *(const float4*)(bgcn + c4);
    float4 o = make_float4(fmaf(hv.x, nn, bb.x), fmaf(hv.y, nn, bb.y),
                           fmaf(hv.z, nn, bb.z), fmaf(hv.w, nn, bb.w));
    *(float4*)(out + (size_t)i * HFEAT + c4) = o;
}

// ---------------- edge scatter: out[dst] += h[src] * dinv[src]*dinv[dst] ----------------
// 32 threads per edge, one float4 per thread -> 4 atomics
__global__ void scatter_kernel(const float* __restrict__ h, const int* __restrict__ src,
                               const int* __restrict__ dst, const float* __restrict__ dinv,
                               float* __restrict__ out, int e) {
    long long idx = (long long)blockIdx.x * blockDim.x + threadIdx.x;
    long long tot = (long long)e * 32;
    if (idx >= tot) return;
    int ed = (int)(idx >> 5);
    int c4 = (int)(idx & 31) * 4;
    int s = src[ed], d = dst[ed];
    float norm = dinv[s] * dinv[d];
    float4 hv = *(const float4*)(h + (size_t)s * HFEAT + c4);
    float* op = out + (size_t)d * HFEAT + c4;
    atomicAdd(op + 0, hv.x * norm);
    atomicAdd(op + 1, hv.y * norm);
    atomicAdd(op + 2, hv.z * norm);
    atomicAdd(op + 3, hv.w * norm);
}

// ---------------- p/q projection: p[i]=out[i,:]·Wa[0:128], q[i]=out[i,:]·Wa[128:256] ----------------
__global__ void pq_kernel(const float* __restrict__ out, const float* __restrict__ Wa,
                          float* __restrict__ p, float* __restrict__ q, int n) {
    int gtid = blockIdx.x * blockDim.x + threadIdx.x;
    int wave = gtid >> 6;
    int lane = threadIdx.x & 63;
    if (wave >= n) return;
    const float* row = out + (size_t)wave * HFEAT;
    float a0 = row[lane], a1 = row[lane + 64];
    float pp = fmaf(a0, Wa[lane], a1 * Wa[lane + 64]);
    float qq = fmaf(a0, Wa[128 + lane], a1 * Wa[192 + lane]);
    for (int off = 32; off; off >>= 1) {
        pp += __shfl_down(pp, off, 64);
        qq += __shfl_down(qq, off, 64);
    }
    if (lane == 0) { p[wave] = pp; q[wave] = qq; }
}

// ---------------- adjacency scores ----------------
__global__ void adj_kernel(const int* __restrict__ k0, const int* __restrict__ k1,
                           const int* __restrict__ na, const float* __restrict__ p,
                           const float* __restrict__ q, const float* __restrict__ ba,
                           float* __restrict__ outp, int ek, int en) {
    int e = blockIdx.x * blockDim.x + threadIdx.x;
    int tot = ek + en;
    if (e >= tot) return;
    int a, b;
    if (e < ek) { a = k0[e]; b = k1[e]; }
    else { int j = e - ek; a = na[2 * j]; b = na[2 * j + 1]; }
    float v = p[a] + q[b] + ba[0];
    outp[e] = 1.f / (1.f + __expf(-v));
}

extern "C" void kernel_launch(void* const* d_in, const int* in_sizes, int n_in,
                              void* d_out, int out_size, void* d_ws, size_t ws_size,
                              hipStream_t stream) {
    const float* x  = (const float*)d_in[0];
    const int*   ei = (const int*)d_in[1];
    const int*   kh = (const int*)d_in[2];
    const int*   na = (const int*)d_in[3];
    const float* Wg = (const float*)d_in[4];
    const float* bg = (const float*)d_in[5];
    const float* W1 = (const float*)d_in[6];
    const float* b1 = (const float*)d_in[7];
    const float* W2 = (const float*)d_in[8];
    const float* b2 = (const float*)d_in[9];
    const float* Wa = (const float*)d_in[10];
    const float* ba = (const float*)d_in[11];

    const int N  = in_sizes[0] / FFEAT;
    const int E  = in_sizes[1] / 2;
    const int EK = in_sizes[2] / 2;
    const int EN = in_sizes[3] / 2;

    float* fo = (float*)d_out;             // feature_out [N, 256]
    float* ao = fo + (size_t)N * FFEAT;    // adj_out [EK+EN]

    float* ws  = (float*)d_ws;
    float* h   = ws;                        // [N,128]
    float* out = h + (size_t)N * HFEAT;     // [N,128]
    float* deg = out + (size_t)N * HFEAT;   // [N] (becomes dinv)
    float* p   = deg + N;                   // [N]
    float* q   = p + N;                     // [N]

    const int B = 256;

    // degree -> dinv
    set_deg_kernel<<<(N + B - 1) / B, B, 0, stream>>>(deg, N);
    count_deg_kernel<<<(E + B - 1) / B, B, 0, stream>>>(ei + E, deg, E);
    rsqrt_kernel<<<(N + B - 1) / B, B, 0, stream>>>(deg, N);

    // h = x @ W_gcn
    gemm_kernel<256, 128, 0><<<(N + 15) / 16, B, 0, stream>>>(x, Wg, nullptr, h, N);

    // out = h * dinv^2 + b_gcn  (self-loop term)
    init_out_kernel<<<(N * 32 + B - 1) / B, B, 0, stream>>>(h, deg, bg, out, N);

    // out[dst] += h[src]*dinv[src]*dinv[dst]
    {
        long long tot = (long long)E * 32;
        int blocks = (int)((tot + B - 1) / B);
        scatter_kernel<<<blocks, B, 0, stream>>>(h, ei, ei + E, deg, out, E);
    }

    // z1 = relu(out@W1+b1)  (reuse h buffer)
    gemm_kernel<128, 128, 1><<<(N + 15) / 16, B, 0, stream>>>(out, W1, b1, h, N);
    // feature_out = sigmoid(z1@W2+b2)
    gemm_kernel<128, 256, 2><<<(N + 15) / 16, B, 0, stream>>>(h, W2, b2, fo, N);

    // p,q per node
    pq_kernel<<<(N + 3) / 4, B, 0, stream>>>(out, Wa, p, q, N);

    // adjacency scores
    adj_kernel<<<(EK + EN + B - 1) / B, B, 0, stream>>>(kh, kh + EK, na, p, q, ba, ao, EK, EN);
}

// Round 3
// 475.898 us; speedup vs baseline: 3.3689x; 3.3689x over previous
//
#include <hip/hip_runtime.h>
#include <cstdint>
#include <cstddef>

#define HFEAT 128
#define FFEAT 256

// ---------------- CSR build ----------------
__global__ void count_kernel(const int* __restrict__ dst, int* __restrict__ cnt, int e) {
    int i = blockIdx.x * blockDim.x + threadIdx.x;
    if (i < e) atomicAdd(&cnt[dst[i]], 1);
}

// single-block exclusive scan over cnt[0..n) -> row_ptr, fill; also dinv = rsqrt(cnt+1)
__global__ __launch_bounds__(1024) void scan_kernel(const int* __restrict__ cnt,
                                                    int* __restrict__ row_ptr,
                                                    int* __restrict__ fill,
                                                    float* __restrict__ dinv, int n) {
    __shared__ int part[1024];
    int t = threadIdx.x;
    int chunk = (n + 1023) >> 10;
    int lo = t * chunk;
    int hi = lo + chunk; if (hi > n) hi = n;
    int s = 0;
    for (int i = lo; i < hi; i++) s += cnt[i];
    part[t] = s;
    __syncthreads();
    for (int off = 1; off < 1024; off <<= 1) {
        int v = (t >= off) ? part[t - off] : 0;
        __syncthreads();
        part[t] += v;
        __syncthreads();
    }
    int excl = (t == 0) ? 0 : part[t - 1];
    for (int i = lo; i < hi; i++) {
        row_ptr[i] = excl;
        fill[i] = excl;
        int c = cnt[i];
        dinv[i] = rsqrtf((float)c + 1.0f);  // +1 for self-loop
        excl += c;
    }
    if (t == 1023) row_ptr[n] = part[1023];
}

__global__ void bucket_kernel(const int* __restrict__ src, const int* __restrict__ dst,
                              int* __restrict__ fill, int* __restrict__ esrc, int e) {
    int i = blockIdx.x * blockDim.x + threadIdx.x;
    if (i < e) {
        int pos = atomicAdd(&fill[dst[i]], 1);
        esrc[pos] = src[i];
    }
}

// ---------------- GEMM: C = act(A[M,K] @ B[K,NCOL] + bias) ----------------
template<int K, int NCOL, int ACT>
__global__ __launch_bounds__(256) void gemm_kernel(
    const float* __restrict__ A, const float* __restrict__ B,
    const float* __restrict__ bias, float* __restrict__ C, int M) {
    constexpr int TM = 16;
    __shared__ float As[TM * K];
    const int row0 = blockIdx.x * TM;
    const int tid = threadIdx.x;
    for (int i = tid; i < (TM * K) / 4; i += 256) {
        int idx = i * 4;
        int r = idx / K, k = idx - r * K;
        int grow = row0 + r;
        float4 v = make_float4(0.f, 0.f, 0.f, 0.f);
        if (grow < M) v = *(const float4*)(A + (size_t)grow * K + k);
        *(float4*)(As + idx) = v;
    }
    __syncthreads();
    constexpr int RPT = (TM * NCOL) / 256;
    const int c = tid % NCOL;
    const int rb = (tid / NCOL) * RPT;
    float acc[RPT];
#pragma unroll
    for (int r = 0; r < RPT; r++) acc[r] = 0.f;
    for (int k = 0; k < K; k++) {
        float bv = B[(size_t)k * NCOL + c];
#pragma unroll
        for (int r = 0; r < RPT; r++)
            acc[r] = fmaf(As[(rb + r) * K + k], bv, acc[r]);
    }
    float bb = bias ? bias[c] : 0.f;
#pragma unroll
    for (int r = 0; r < RPT; r++) {
        int grow = row0 + rb + r;
        if (grow >= M) continue;
        float v = acc[r] + bb;
        if (ACT == 1) v = v > 0.f ? v : 0.f;
        if (ACT == 2) v = 1.f / (1.f + __expf(-v));
        C[(size_t)grow * NCOL + c] = v;
    }
}

// ---------------- CSR gather: out[d] = dinv[d]*(sum_{s in in(d)} h[s]*dinv[s] + h[d]*dinv[d]) + bg
// 8 nodes per 256-thread block; 32 threads/node, float4 per thread
__global__ __launch_bounds__(256) void gather_kernel(
    const float* __restrict__ h, const int* __restrict__ row_ptr,
    const int* __restrict__ esrc, const float* __restrict__ dinv,
    const float* __restrict__ bg, float* __restrict__ out, int n) {
    int tid = threadIdx.x;
    int node = blockIdx.x * 8 + (tid >> 5);
    int c4 = (tid & 31) * 4;
    if (node >= n) return;
    float di = dinv[node];
    int r0 = row_ptr[node], r1 = row_ptr[node + 1];
    float4 hv = *(const float4*)(h + (size_t)node * HFEAT + c4);
    float4 acc = make_float4(hv.x * di, hv.y * di, hv.z * di, hv.w * di);
    int e = r0;
    for (; e + 1 < r1; e += 2) {
        int s0 = esrc[e], s1 = esrc[e + 1];
        float d0 = dinv[s0], d1 = dinv[s1];
        float4 v0 = *(const float4*)(h + (size_t)s0 * HFEAT + c4);
        float4 v1 = *(const float4*)(h + (size_t)s1 * HFEAT + c4);
        acc.x = fmaf(v0.x, d0, acc.x); acc.y = fmaf(v0.y, d0, acc.y);
        acc.z = fmaf(v0.z, d0, acc.z); acc.w = fmaf(v0.w, d0, acc.w);
        acc.x = fmaf(v1.x, d1, acc.x); acc.y = fmaf(v1.y, d1, acc.y);
        acc.z = fmaf(v1.z, d1, acc.z); acc.w = fmaf(v1.w, d1, acc.w);
    }
    if (e < r1) {
        int s0 = esrc[e];
        float d0 = dinv[s0];
        float4 v0 = *(const float4*)(h + (size_t)s0 * HFEAT + c4);
        acc.x = fmaf(v0.x, d0, acc.x); acc.y = fmaf(v0.y, d0, acc.y);
        acc.z = fmaf(v0.z, d0, acc.z); acc.w = fmaf(v0.w, d0, acc.w);
    }
    float4 bb = *(const float4*)(bg + c4);
    float4 o = make_float4(fmaf(acc.x, di, bb.x), fmaf(acc.y, di, bb.y),
                           fmaf(acc.z, di, bb.z), fmaf(acc.w, di, bb.w));
    *(float4*)(out + (size_t)node * HFEAT + c4) = o;
}

// ---------------- p/q projection ----------------
__global__ void pq_kernel(const float* __restrict__ out, const float* __restrict__ Wa,
                          float* __restrict__ p, float* __restrict__ q, int n) {
    int gtid = blockIdx.x * blockDim.x + threadIdx.x;
    int wave = gtid >> 6;
    int lane = threadIdx.x & 63;
    if (wave >= n) return;
    const float* row = out + (size_t)wave * HFEAT;
    float a0 = row[lane], a1 = row[lane + 64];
    float pp = fmaf(a0, Wa[lane], a1 * Wa[lane + 64]);
    float qq = fmaf(a0, Wa[128 + lane], a1 * Wa[192 + lane]);
    for (int off = 32; off; off >>= 1) {
        pp += __shfl_down(pp, off, 64);
        qq += __shfl_down(qq, off, 64);
    }
    if (lane == 0) { p[wave] = pp; q[wave] = qq; }
}

// ---------------- adjacency scores ----------------
__global__ void adj_kernel(const int* __restrict__ k0, const int* __restrict__ k1,
                           const int* __restrict__ na, const float* __restrict__ p,
                           const float* __restrict__ q, const float* __restrict__ ba,
                           float* __restrict__ outp, int ek, int en) {
    int e = blockIdx.x * blockDim.x + threadIdx.x;
    int tot = ek + en;
    if (e >= tot) return;
    int a, b;
    if (e < ek) { a = k0[e]; b = k1[e]; }
    else { int j = e - ek; a = na[2 * j]; b = na[2 * j + 1]; }
    float v = p[a] + q[b] + ba[0];
    outp[e] = 1.f / (1.f + __expf(-v));
}

extern "C" void kernel_launch(void* const* d_in, const int* in_sizes, int n_in,
                              void* d_out, int out_size, void* d_ws, size_t ws_size,
                              hipStream_t stream) {
    const float* x  = (const float*)d_in[0];
    const int*   ei = (const int*)d_in[1];
    const int*   kh = (const int*)d_in[2];
    const int*   na = (const int*)d_in[3];
    const float* Wg = (const float*)d_in[4];
    const float* bg = (const float*)d_in[5];
    const float* W1 = (const float*)d_in[6];
    const float* b1 = (const float*)d_in[7];
    const float* W2 = (const float*)d_in[8];
    const float* b2 = (const float*)d_in[9];
    const float* Wa = (const float*)d_in[10];
    const float* ba = (const float*)d_in[11];

    const int N  = in_sizes[0] / FFEAT;
    const int E  = in_sizes[1] / 2;
    const int EK = in_sizes[2] / 2;
    const int EN = in_sizes[3] / 2;

    float* fo = (float*)d_out;             // feature_out [N, 256]
    float* ao = fo + (size_t)N * FFEAT;    // adj_out [EK+EN]

    char* ws = (char*)d_ws;
    float* h       = (float*)ws;                  ws += (size_t)N * HFEAT * 4;  // [N,128]
    float* out     = (float*)ws;                  ws += (size_t)N * HFEAT * 4;  // [N,128]
    float* dinv    = (float*)ws;                  ws += (size_t)N * 4;
    float* p       = (float*)ws;                  ws += (size_t)N * 4;
    float* q       = (float*)ws;                  ws += (size_t)N * 4;
    int*   cnt     = (int*)ws;                    ws += (size_t)N * 4;
    int*   row_ptr = (int*)ws;                    ws += (size_t)(N + 1) * 4;
    int*   fill    = (int*)ws;                    ws += (size_t)N * 4;
    int*   esrc    = (int*)ws;                    ws += (size_t)E * 4;

    const int B = 256;

    // CSR build
    hipMemsetAsync(cnt, 0, (size_t)N * 4, stream);
    count_kernel<<<(E + B - 1) / B, B, 0, stream>>>(ei + E, cnt, E);
    scan_kernel<<<1, 1024, 0, stream>>>(cnt, row_ptr, fill, dinv, N);
    bucket_kernel<<<(E + B - 1) / B, B, 0, stream>>>(ei, ei + E, fill, esrc, E);

    // h = x @ W_gcn
    gemm_kernel<256, 128, 0><<<(N + 15) / 16, B, 0, stream>>>(x, Wg, nullptr, h, N);

    // out = GCN aggregate (self-loop + in-edges), fused bias
    gather_kernel<<<(N + 7) / 8, B, 0, stream>>>(h, row_ptr, esrc, dinv, bg, out, N);

    // z1 = relu(out@W1+b1)  (reuse h buffer)
    gemm_kernel<128, 128, 1><<<(N + 15) / 16, B, 0, stream>>>(out, W1, b1, h, N);
    // feature_out = sigmoid(z1@W2+b2)
    gemm_kernel<128, 256, 2><<<(N + 15) / 16, B, 0, stream>>>(h, W2, b2, fo, N);

    // p,q per node
    pq_kernel<<<(N + 3) / 4, B, 0, stream>>>(out, Wa, p, q, N);

    // adjacency scores
    adj_kernel<<<(EK + EN + B - 1) / B, B, 0, stream>>>(kh, kh + EK, na, p, q, ba, ao, EK, EN);
}

// Round 4
// 355.183 us; speedup vs baseline: 4.5139x; 1.3399x over previous
//
#include <hip/hip_runtime.h>
#include <cstdint>
#include <cstddef>

#define HFEAT 128
#define FFEAT 256

// ---------------- CSR build ----------------
__global__ void count_kernel(const int* __restrict__ dst, int* __restrict__ cnt, int e) {
    int i = blockIdx.x * blockDim.x + threadIdx.x;
    if (i < e) atomicAdd(&cnt[dst[i]], 1);
}

// Phase 1: per-block sums of cnt (256 elems/block)
__global__ __launch_bounds__(256) void bsum_kernel(const int* __restrict__ cnt,
                                                   int* __restrict__ bsum, int n) {
    int i = blockIdx.x * 256 + threadIdx.x;
    int v = (i < n) ? cnt[i] : 0;
    for (int off = 32; off; off >>= 1) v += __shfl_down(v, off, 64);
    __shared__ int sh[4];
    if ((threadIdx.x & 63) == 0) sh[threadIdx.x >> 6] = v;
    __syncthreads();
    if (threadIdx.x == 0) bsum[blockIdx.x] = sh[0] + sh[1] + sh[2] + sh[3];
}

// Phase 2: exclusive scan of block sums (nb <= 1024), single block
__global__ __launch_bounds__(1024) void bscan_kernel(int* __restrict__ bsum, int nb) {
    __shared__ int sh[1024];
    int t = threadIdx.x;
    int v = (t < nb) ? bsum[t] : 0;
    sh[t] = v;
    __syncthreads();
    for (int off = 1; off < 1024; off <<= 1) {
        int u = (t >= off) ? sh[t - off] : 0;
        __syncthreads();
        sh[t] += u;
        __syncthreads();
    }
    if (t < nb) bsum[t] = sh[t] - v;  // exclusive
}

// Phase 3: block-local scan + offset; write row_ptr, fill, dinv
__global__ __launch_bounds__(256) void scanw_kernel(const int* __restrict__ cnt,
                                                    const int* __restrict__ boff,
                                                    int* __restrict__ row_ptr,
                                                    int* __restrict__ fill,
                                                    float* __restrict__ dinv, int n) {
    __shared__ int sh[256];
    int t = threadIdx.x;
    int i = blockIdx.x * 256 + t;
    int v = (i < n) ? cnt[i] : 0;
    sh[t] = v;
    __syncthreads();
    for (int off = 1; off < 256; off <<= 1) {
        int u = (t >= off) ? sh[t - off] : 0;
        __syncthreads();
        sh[t] += u;
        __syncthreads();
    }
    int excl = boff[blockIdx.x] + sh[t] - v;
    if (i < n) {
        row_ptr[i] = excl;
        fill[i] = excl;
        dinv[i] = rsqrtf((float)v + 1.0f);  // +1 self-loop
        if (i == n - 1) row_ptr[n] = excl + v;
    }
}

__global__ void bucket_kernel(const int* __restrict__ src, const int* __restrict__ dst,
                              int* __restrict__ fill, int* __restrict__ esrc, int e) {
    int i = blockIdx.x * blockDim.x + threadIdx.x;
    if (i < e) {
        int pos = atomicAdd(&fill[dst[i]], 1);
        esrc[pos] = src[i];
    }
}

// ---------------- GEMM: C = act(A[M,K] @ B[K,NCOL] + bias) ----------------
template<int K, int NCOL, int ACT>
__global__ __launch_bounds__(256) void gemm_kernel(
    const float* __restrict__ A, const float* __restrict__ B,
    const float* __restrict__ bias, float* __restrict__ C, int M) {
    constexpr int TM = 16;
    __shared__ float As[TM * K];
    const int row0 = blockIdx.x * TM;
    const int tid = threadIdx.x;
    for (int i = tid; i < (TM * K) / 4; i += 256) {
        int idx = i * 4;
        int r = idx / K, k = idx - r * K;
        int grow = row0 + r;
        float4 v = make_float4(0.f, 0.f, 0.f, 0.f);
        if (grow < M) v = *(const float4*)(A + (size_t)grow * K + k);
        *(float4*)(As + idx) = v;
    }
    __syncthreads();
    constexpr int RPT = (TM * NCOL) / 256;
    const int c = tid % NCOL;
    const int rb = (tid / NCOL) * RPT;
    float acc[RPT];
#pragma unroll
    for (int r = 0; r < RPT; r++) acc[r] = 0.f;
    for (int k = 0; k < K; k++) {
        float bv = B[(size_t)k * NCOL + c];
#pragma unroll
        for (int r = 0; r < RPT; r++)
            acc[r] = fmaf(As[(rb + r) * K + k], bv, acc[r]);
    }
    float bb = bias ? bias[c] : 0.f;
#pragma unroll
    for (int r = 0; r < RPT; r++) {
        int grow = row0 + rb + r;
        if (grow >= M) continue;
        float v = acc[r] + bb;
        if (ACT == 1) v = v > 0.f ? v : 0.f;
        if (ACT == 2) v = 1.f / (1.f + __expf(-v));
        C[(size_t)grow * NCOL + c] = v;
    }
}

// ---------------- CSR gather ----------------
__global__ __launch_bounds__(256) void gather_kernel(
    const float* __restrict__ h, const int* __restrict__ row_ptr,
    const int* __restrict__ esrc, const float* __restrict__ dinv,
    const float* __restrict__ bg, float* __restrict__ out, int n) {
    int tid = threadIdx.x;
    int node = blockIdx.x * 8 + (tid >> 5);
    int c4 = (tid & 31) * 4;
    if (node >= n) return;
    float di = dinv[node];
    int r0 = row_ptr[node], r1 = row_ptr[node + 1];
    float4 hv = *(const float4*)(h + (size_t)node * HFEAT + c4);
    float4 acc = make_float4(hv.x * di, hv.y * di, hv.z * di, hv.w * di);
    int e = r0;
    for (; e + 1 < r1; e += 2) {
        int s0 = esrc[e], s1 = esrc[e + 1];
        float d0 = dinv[s0], d1 = dinv[s1];
        float4 v0 = *(const float4*)(h + (size_t)s0 * HFEAT + c4);
        float4 v1 = *(const float4*)(h + (size_t)s1 * HFEAT + c4);
        acc.x = fmaf(v0.x, d0, acc.x); acc.y = fmaf(v0.y, d0, acc.y);
        acc.z = fmaf(v0.z, d0, acc.z); acc.w = fmaf(v0.w, d0, acc.w);
        acc.x = fmaf(v1.x, d1, acc.x); acc.y = fmaf(v1.y, d1, acc.y);
        acc.z = fmaf(v1.z, d1, acc.z); acc.w = fmaf(v1.w, d1, acc.w);
    }
    if (e < r1) {
        int s0 = esrc[e];
        float d0 = dinv[s0];
        float4 v0 = *(const float4*)(h + (size_t)s0 * HFEAT + c4);
        acc.x = fmaf(v0.x, d0, acc.x); acc.y = fmaf(v0.y, d0, acc.y);
        acc.z = fmaf(v0.z, d0, acc.z); acc.w = fmaf(v0.w, d0, acc.w);
    }
    float4 bb = *(const float4*)(bg + c4);
    float4 o = make_float4(fmaf(acc.x, di, bb.x), fmaf(acc.y, di, bb.y),
                           fmaf(acc.z, di, bb.z), fmaf(acc.w, di, bb.w));
    *(float4*)(out + (size_t)node * HFEAT + c4) = o;
}

// ---------------- p/q projection ----------------
__global__ void pq_kernel(const float* __restrict__ out, const float* __restrict__ Wa,
                          float* __restrict__ p, float* __restrict__ q, int n) {
    int gtid = blockIdx.x * blockDim.x + threadIdx.x;
    int wave = gtid >> 6;
    int lane = threadIdx.x & 63;
    if (wave >= n) return;
    const float* row = out + (size_t)wave * HFEAT;
    float a0 = row[lane], a1 = row[lane + 64];
    float pp = fmaf(a0, Wa[lane], a1 * Wa[lane + 64]);
    float qq = fmaf(a0, Wa[128 + lane], a1 * Wa[192 + lane]);
    for (int off = 32; off; off >>= 1) {
        pp += __shfl_down(pp, off, 64);
        qq += __shfl_down(qq, off, 64);
    }
    if (lane == 0) { p[wave] = pp; q[wave] = qq; }
}

// ---------------- adjacency scores ----------------
__global__ void adj_kernel(const int* __restrict__ k0, const int* __restrict__ k1,
                           const int* __restrict__ na, const float* __restrict__ p,
                           const float* __restrict__ q, const float* __restrict__ ba,
                           float* __restrict__ outp, int ek, int en) {
    int e = blockIdx.x * blockDim.x + threadIdx.x;
    int tot = ek + en;
    if (e >= tot) return;
    int a, b;
    if (e < ek) { a = k0[e]; b = k1[e]; }
    else { int j = e - ek; a = na[2 * j]; b = na[2 * j + 1]; }
    float v = p[a] + q[b] + ba[0];
    outp[e] = 1.f / (1.f + __expf(-v));
}

extern "C" void kernel_launch(void* const* d_in, const int* in_sizes, int n_in,
                              void* d_out, int out_size, void* d_ws, size_t ws_size,
                              hipStream_t stream) {
    const float* x  = (const float*)d_in[0];
    const int*   ei = (const int*)d_in[1];
    const int*   kh = (const int*)d_in[2];
    const int*   na = (const int*)d_in[3];
    const float* Wg = (const float*)d_in[4];
    const float* bg = (const float*)d_in[5];
    const float* W1 = (const float*)d_in[6];
    const float* b1 = (const float*)d_in[7];
    const float* W2 = (const float*)d_in[8];
    const float* b2 = (const float*)d_in[9];
    const float* Wa = (const float*)d_in[10];
    const float* ba = (const float*)d_in[11];

    const int N  = in_sizes[0] / FFEAT;
    const int E  = in_sizes[1] / 2;
    const int EK = in_sizes[2] / 2;
    const int EN = in_sizes[3] / 2;

    float* fo = (float*)d_out;             // feature_out [N, 256]
    float* ao = fo + (size_t)N * FFEAT;    // adj_out [EK+EN]

    char* ws = (char*)d_ws;
    float* h       = (float*)ws;                  ws += (size_t)N * HFEAT * 4;
    float* out     = (float*)ws;                  ws += (size_t)N * HFEAT * 4;
    float* dinv    = (float*)ws;                  ws += (size_t)N * 4;
    float* p       = (float*)ws;                  ws += (size_t)N * 4;
    float* q       = (float*)ws;                  ws += (size_t)N * 4;
    int*   cnt     = (int*)ws;                    ws += (size_t)N * 4;
    int*   row_ptr = (int*)ws;                    ws += (size_t)(N + 1) * 4;
    int*   fill    = (int*)ws;                    ws += (size_t)N * 4;
    int*   bsum    = (int*)ws;                    ws += (size_t)1024 * 4;
    int*   esrc    = (int*)ws;                    ws += (size_t)E * 4;

    const int B = 256;
    const int NB = (N + 255) / 256;  // scan blocks (196 for N=50000, fits <=1024)

    // CSR build
    hipMemsetAsync(cnt, 0, (size_t)N * 4, stream);
    count_kernel<<<(E + B - 1) / B, B, 0, stream>>>(ei + E, cnt, E);
    bsum_kernel<<<NB, B, 0, stream>>>(cnt, bsum, N);
    bscan_kernel<<<1, 1024, 0, stream>>>(bsum, NB);
    scanw_kernel<<<NB, B, 0, stream>>>(cnt, bsum, row_ptr, fill, dinv, N);
    bucket_kernel<<<(E + B - 1) / B, B, 0, stream>>>(ei, ei + E, fill, esrc, E);

    // h = x @ W_gcn
    gemm_kernel<256, 128, 0><<<(N + 15) / 16, B, 0, stream>>>(x, Wg, nullptr, h, N);

    // out = GCN aggregate (self-loop + in-edges), fused bias
    gather_kernel<<<(N + 7) / 8, B, 0, stream>>>(h, row_ptr, esrc, dinv, bg, out, N);

    // z1 = relu(out@W1+b1)  (reuse h buffer)
    gemm_kernel<128, 128, 1><<<(N + 15) / 16, B, 0, stream>>>(out, W1, b1, h, N);
    // feature_out = sigmoid(z1@W2+b2)
    gemm_kernel<128, 256, 2><<<(N + 15) / 16, B, 0, stream>>>(h, W2, b2, fo, N);

    // p,q per node
    pq_kernel<<<(N + 3) / 4, B, 0, stream>>>(out, Wa, p, q, N);

    // adjacency scores
    adj_kernel<<<(EK + EN + B - 1) / B, B, 0, stream>>>(kh, kh + EK, na, p, q, ba, ao, EK, EN);
}

// Round 5
// 244.798 us; speedup vs baseline: 6.5492x; 1.4509x over previous
//
#include <hip/hip_runtime.h>
#include <cstdint>
#include <cstddef>

#define HFEAT 128
#define FFEAT 256

typedef short bf16x8 __attribute__((ext_vector_type(8)));
typedef float f32x4 __attribute__((ext_vector_type(4)));

static __device__ __forceinline__ unsigned short f2bf(float f) {
    unsigned u = __float_as_uint(f);
    unsigned r = (u + 0x7fff + ((u >> 16) & 1)) >> 16;  // RNE
    return (unsigned short)r;
}
static __device__ __forceinline__ float bf2f(unsigned short u) {
    return __uint_as_float((unsigned)u << 16);
}

// ---------------- CSR build ----------------
__global__ void count_kernel(const int* __restrict__ dst, int* __restrict__ cnt, int e) {
    int i = blockIdx.x * blockDim.x + threadIdx.x;
    if (i < e) atomicAdd(&cnt[dst[i]], 1);
}

__global__ __launch_bounds__(256) void bsum_kernel(const int* __restrict__ cnt,
                                                   int* __restrict__ bsum, int n) {
    int i = blockIdx.x * 256 + threadIdx.x;
    int v = (i < n) ? cnt[i] : 0;
    for (int off = 32; off; off >>= 1) v += __shfl_down(v, off, 64);
    __shared__ int sh[4];
    if ((threadIdx.x & 63) == 0) sh[threadIdx.x >> 6] = v;
    __syncthreads();
    if (threadIdx.x == 0) bsum[blockIdx.x] = sh[0] + sh[1] + sh[2] + sh[3];
}

__global__ __launch_bounds__(1024) void bscan_kernel(int* __restrict__ bsum, int nb) {
    __shared__ int sh[1024];
    int t = threadIdx.x;
    int v = (t < nb) ? bsum[t] : 0;
    sh[t] = v;
    __syncthreads();
    for (int off = 1; off < 1024; off <<= 1) {
        int u = (t >= off) ? sh[t - off] : 0;
        __syncthreads();
        sh[t] += u;
        __syncthreads();
    }
    if (t < nb) bsum[t] = sh[t] - v;  // exclusive
}

__global__ __launch_bounds__(256) void scanw_kernel(const int* __restrict__ cnt,
                                                    const int* __restrict__ boff,
                                                    int* __restrict__ row_ptr,
                                                    int* __restrict__ fill,
                                                    float* __restrict__ dinv, int n) {
    __shared__ int sh[256];
    int t = threadIdx.x;
    int i = blockIdx.x * 256 + t;
    int v = (i < n) ? cnt[i] : 0;
    sh[t] = v;
    __syncthreads();
    for (int off = 1; off < 256; off <<= 1) {
        int u = (t >= off) ? sh[t - off] : 0;
        __syncthreads();
        sh[t] += u;
        __syncthreads();
    }
    int excl = boff[blockIdx.x] + sh[t] - v;
    if (i < n) {
        row_ptr[i] = excl;
        fill[i] = excl;
        dinv[i] = rsqrtf((float)v + 1.0f);
        if (i == n - 1) row_ptr[n] = excl + v;
    }
}

__global__ void bucket_kernel(const int* __restrict__ src, const int* __restrict__ dst,
                              int* __restrict__ fill, int* __restrict__ esrc, int e) {
    int i = blockIdx.x * blockDim.x + threadIdx.x;
    if (i < e) {
        int pos = atomicAdd(&fill[dst[i]], 1);
        esrc[pos] = src[i];
    }
}

// ---------------- bf16 convert / weight pack ----------------
__global__ void cvt_bf16_kernel(const float* __restrict__ in, ushort* __restrict__ out, int n4) {
    int i = blockIdx.x * blockDim.x + threadIdx.x;
    if (i >= n4) return;
    float4 v = ((const float4*)in)[i];
    ushort4 o;
    o.x = f2bf(v.x); o.y = f2bf(v.y); o.z = f2bf(v.z); o.w = f2bf(v.w);
    ((ushort4*)out)[i] = o;
}

// pack W[K,N] f32 -> Bp bf16 fragment layout: [(kt*N/16+ct)*64+lane][8]
// lane holds B[kt*32 + 8*(lane>>4)+j][ct*16 + (lane&15)]
__global__ void pack_b_kernel(const float* __restrict__ W, ushort* __restrict__ Bp,
                              int K, int N) {
    int tid = blockIdx.x * blockDim.x + threadIdx.x;
    if (tid >= K * N) return;
    int j = tid & 7;
    int lane = (tid >> 3) & 63;
    int rest = tid >> 9;
    int nct = N >> 4;
    int ct = rest % nct, kt = rest / nct;
    int k = kt * 32 + (lane >> 4) * 8 + j;
    int col = ct * 16 + (lane & 15);
    Bp[tid] = f2bf(W[(size_t)k * N + col]);
}

// ---------------- MFMA GEMM: C = act(A[M,K]bf16 @ B[K,NTOT]) ----------------
// block = 256 thr (4 waves); wave computes 32 rows x 64 cols (NCT=4 col-tiles)
// grid: x = ceil(M/128), y = totct/4
template<int K, int ACT>
__global__ __launch_bounds__(256) void mfma_gemm(
    const ushort* __restrict__ A, const ushort* __restrict__ Bp,
    const float* __restrict__ bias, void* __restrict__ Cout,
    int M, int ldc, int totct) {
    constexpr int NCT = 4;
    const int tid = threadIdx.x;
    const int wid = tid >> 6, lane = tid & 63;
    const int ct0 = blockIdx.y * NCT;
    const int rowbase = blockIdx.x * 128 + wid * 32;
    const int ak = (lane >> 4) * 8;

    f32x4 acc[2][NCT];
#pragma unroll
    for (int s = 0; s < 2; s++)
#pragma unroll
        for (int c = 0; c < NCT; c++) acc[s][c] = (f32x4){0.f, 0.f, 0.f, 0.f};

    int r0 = rowbase + (lane & 15); if (r0 >= M) r0 = M - 1;
    int r1 = rowbase + 16 + (lane & 15); if (r1 >= M) r1 = M - 1;
    const ushort* a0p = A + (size_t)r0 * K + ak;
    const ushort* a1p = A + (size_t)r1 * K + ak;

#pragma unroll
    for (int kt = 0; kt < K / 32; kt++) {
        bf16x8 a0 = *reinterpret_cast<const bf16x8*>(a0p + kt * 32);
        bf16x8 a1 = *reinterpret_cast<const bf16x8*>(a1p + kt * 32);
        const ushort* bp = Bp + ((size_t)(kt * totct + ct0) * 64 + lane) * 8;
#pragma unroll
        for (int c = 0; c < NCT; c++) {
            bf16x8 b = *reinterpret_cast<const bf16x8*>(bp + (size_t)c * 64 * 8);
            acc[0][c] = __builtin_amdgcn_mfma_f32_16x16x32_bf16(a0, b, acc[0][c], 0, 0, 0);
            acc[1][c] = __builtin_amdgcn_mfma_f32_16x16x32_bf16(a1, b, acc[1][c], 0, 0, 0);
        }
    }

    const int ccol = lane & 15;
    const int crow = (lane >> 4) * 4;
#pragma unroll
    for (int s = 0; s < 2; s++) {
#pragma unroll
        for (int c = 0; c < NCT; c++) {
            int col = (ct0 + c) * 16 + ccol;
            float bb = bias ? bias[col] : 0.f;
#pragma unroll
            for (int r = 0; r < 4; r++) {
                int row = rowbase + s * 16 + crow + r;
                if (row >= M) continue;
                float v = acc[s][c][r] + bb;
                if (ACT == 1) {
                    v = v > 0.f ? v : 0.f;
                    ((ushort*)Cout)[(size_t)row * ldc + col] = f2bf(v);
                } else if (ACT == 2) {
                    v = 1.f / (1.f + __expf(-v));
                    ((float*)Cout)[(size_t)row * ldc + col] = v;
                } else {
                    ((float*)Cout)[(size_t)row * ldc + col] = v;
                }
            }
        }
    }
}

// ---------------- CSR gather -> bf16 out ----------------
__global__ __launch_bounds__(256) void gather_kernel(
    const float* __restrict__ h, const int* __restrict__ row_ptr,
    const int* __restrict__ esrc, const float* __restrict__ dinv,
    const float* __restrict__ bg, ushort* __restrict__ outb, int n) {
    int tid = threadIdx.x;
    int node = blockIdx.x * 8 + (tid >> 5);
    int c4 = (tid & 31) * 4;
    if (node >= n) return;
    float di = dinv[node];
    int r0 = row_ptr[node], r1 = row_ptr[node + 1];
    float4 hv = *(const float4*)(h + (size_t)node * HFEAT + c4);
    float4 acc = make_float4(hv.x * di, hv.y * di, hv.z * di, hv.w * di);
    int e = r0;
    for (; e + 1 < r1; e += 2) {
        int s0 = esrc[e], s1 = esrc[e + 1];
        float d0 = dinv[s0], d1 = dinv[s1];
        float4 v0 = *(const float4*)(h + (size_t)s0 * HFEAT + c4);
        float4 v1 = *(const float4*)(h + (size_t)s1 * HFEAT + c4);
        acc.x = fmaf(v0.x, d0, acc.x); acc.y = fmaf(v0.y, d0, acc.y);
        acc.z = fmaf(v0.z, d0, acc.z); acc.w = fmaf(v0.w, d0, acc.w);
        acc.x = fmaf(v1.x, d1, acc.x); acc.y = fmaf(v1.y, d1, acc.y);
        acc.z = fmaf(v1.z, d1, acc.z); acc.w = fmaf(v1.w, d1, acc.w);
    }
    if (e < r1) {
        int s0 = esrc[e];
        float d0 = dinv[s0];
        float4 v0 = *(const float4*)(h + (size_t)s0 * HFEAT + c4);
        acc.x = fmaf(v0.x, d0, acc.x); acc.y = fmaf(v0.y, d0, acc.y);
        acc.z = fmaf(v0.z, d0, acc.z); acc.w = fmaf(v0.w, d0, acc.w);
    }
    float4 bb = *(const float4*)(bg + c4);
    ushort4 o;
    o.x = f2bf(fmaf(acc.x, di, bb.x));
    o.y = f2bf(fmaf(acc.y, di, bb.y));
    o.z = f2bf(fmaf(acc.z, di, bb.z));
    o.w = f2bf(fmaf(acc.w, di, bb.w));
    *(ushort4*)(outb + (size_t)node * HFEAT + c4) = o;
}

// ---------------- p/q projection (bf16 out) ----------------
__global__ void pq_kernel(const ushort* __restrict__ outb, const float* __restrict__ Wa,
                          float* __restrict__ p, float* __restrict__ q, int n) {
    int gtid = blockIdx.x * blockDim.x + threadIdx.x;
    int wave = gtid >> 6;
    int lane = threadIdx.x & 63;
    if (wave >= n) return;
    const ushort* row = outb + (size_t)wave * HFEAT;
    float a0 = bf2f(row[lane]), a1 = bf2f(row[lane + 64]);
    float pp = fmaf(a0, Wa[lane], a1 * Wa[lane + 64]);
    float qq = fmaf(a0, Wa[128 + lane], a1 * Wa[192 + lane]);
    for (int off = 32; off; off >>= 1) {
        pp += __shfl_down(pp, off, 64);
        qq += __shfl_down(qq, off, 64);
    }
    if (lane == 0) { p[wave] = pp; q[wave] = qq; }
}

// ---------------- adjacency scores ----------------
__global__ void adj_kernel(const int* __restrict__ k0, const int* __restrict__ k1,
                           const int* __restrict__ na, const float* __restrict__ p,
                           const float* __restrict__ q, const float* __restrict__ ba,
                           float* __restrict__ outp, int ek, int en) {
    int e = blockIdx.x * blockDim.x + threadIdx.x;
    int tot = ek + en;
    if (e >= tot) return;
    int a, b;
    if (e < ek) { a = k0[e]; b = k1[e]; }
    else { int j = e - ek; a = na[2 * j]; b = na[2 * j + 1]; }
    float v = p[a] + q[b] + ba[0];
    outp[e] = 1.f / (1.f + __expf(-v));
}

extern "C" void kernel_launch(void* const* d_in, const int* in_sizes, int n_in,
                              void* d_out, int out_size, void* d_ws, size_t ws_size,
                              hipStream_t stream) {
    const float* x  = (const float*)d_in[0];
    const int*   ei = (const int*)d_in[1];
    const int*   kh = (const int*)d_in[2];
    const int*   na = (const int*)d_in[3];
    const float* Wg = (const float*)d_in[4];
    const float* bg = (const float*)d_in[5];
    const float* W1 = (const float*)d_in[6];
    const float* b1 = (const float*)d_in[7];
    const float* W2 = (const float*)d_in[8];
    const float* b2 = (const float*)d_in[9];
    const float* Wa = (const float*)d_in[10];
    const float* ba = (const float*)d_in[11];

    const int N  = in_sizes[0] / FFEAT;
    const int E  = in_sizes[1] / 2;
    const int EK = in_sizes[2] / 2;
    const int EN = in_sizes[3] / 2;

    float* fo = (float*)d_out;             // feature_out [N, 256] f32
    float* ao = fo + (size_t)N * FFEAT;    // adj_out [EK+EN]

    char* ws = (char*)d_ws;
    float*  h    = (float*)ws;   ws += (size_t)N * HFEAT * 4;   // 25.6 MB
    ushort* xb   = (ushort*)ws;  ws += (size_t)N * FFEAT * 2;   // 25.6 MB (reused as zb)
    ushort* outb = (ushort*)ws;  ws += (size_t)N * HFEAT * 2;   // 12.8 MB
    ushort* WgP  = (ushort*)ws;  ws += (size_t)FFEAT * HFEAT * 2;
    ushort* W1P  = (ushort*)ws;  ws += (size_t)HFEAT * HFEAT * 2;
    ushort* W2P  = (ushort*)ws;  ws += (size_t)HFEAT * FFEAT * 2;
    float*  dinv = (float*)ws;   ws += (size_t)N * 4;
    float*  p    = (float*)ws;   ws += (size_t)N * 4;
    float*  q    = (float*)ws;   ws += (size_t)N * 4;
    int*    cnt  = (int*)ws;     ws += (size_t)N * 4;
    int*    row_ptr = (int*)ws;  ws += (size_t)(N + 1) * 4;
    int*    fill = (int*)ws;     ws += (size_t)N * 4;
    int*    bsum = (int*)ws;     ws += (size_t)1024 * 4;
    int*    esrc = (int*)ws;     ws += (size_t)E * 4;
    ushort* zb = xb;  // z1 bf16, reuses xb (dead after G1)

    const int B = 256;
    const int NB = (N + 255) / 256;
    const int GX = (N + 127) / 128;

    // CSR build
    hipMemsetAsync(cnt, 0, (size_t)N * 4, stream);
    count_kernel<<<(E + B - 1) / B, B, 0, stream>>>(ei + E, cnt, E);
    bsum_kernel<<<NB, B, 0, stream>>>(cnt, bsum, N);
    bscan_kernel<<<1, 1024, 0, stream>>>(bsum, NB);
    scanw_kernel<<<NB, B, 0, stream>>>(cnt, bsum, row_ptr, fill, dinv, N);
    bucket_kernel<<<(E + B - 1) / B, B, 0, stream>>>(ei, ei + E, fill, esrc, E);

    // bf16 conversions / weight packs
    cvt_bf16_kernel<<<(N * FFEAT / 4 + B - 1) / B, B, 0, stream>>>(x, xb, N * FFEAT / 4);
    pack_b_kernel<<<(FFEAT * HFEAT + B - 1) / B, B, 0, stream>>>(Wg, WgP, FFEAT, HFEAT);
    pack_b_kernel<<<(HFEAT * HFEAT + B - 1) / B, B, 0, stream>>>(W1, W1P, HFEAT, HFEAT);
    pack_b_kernel<<<(HFEAT * FFEAT + B - 1) / B, B, 0, stream>>>(W2, W2P, HFEAT, FFEAT);

    // G1: h = xb @ Wg   [M,256]@[256,128] -> f32
    mfma_gemm<FFEAT, 0><<<dim3(GX, 2), B, 0, stream>>>(xb, WgP, nullptr, h, N, HFEAT, HFEAT / 16);

    // GCN aggregate -> outb (bf16), bias fused
    gather_kernel<<<(N + 7) / 8, B, 0, stream>>>(h, row_ptr, esrc, dinv, bg, outb, N);

    // G2: zb = relu(outb @ W1 + b1) -> bf16
    mfma_gemm<HFEAT, 1><<<dim3(GX, 2), B, 0, stream>>>(outb, W1P, b1, zb, N, HFEAT, HFEAT / 16);

    // G3: fo = sigmoid(zb @ W2 + b2) -> f32
    mfma_gemm<HFEAT, 2><<<dim3(GX, 4), B, 0, stream>>>(zb, W2P, b2, fo, N, FFEAT, FFEAT / 16);

    // p,q per node
    pq_kernel<<<(N + 3) / 4, B, 0, stream>>>(outb, Wa, p, q, N);

    // adjacency scores
    adj_kernel<<<(EK + EN + B - 1) / B, B, 0, stream>>>(kh, kh + EK, na, p, q, ba, ao, EK, EN);
}

// Round 6
// 227.054 us; speedup vs baseline: 7.0611x; 1.0781x over previous
//
#include <hip/hip_runtime.h>
#include <cstdint>
#include <cstddef>

#define HFEAT 128
#define FFEAT 256

typedef short bf16x8 __attribute__((ext_vector_type(8)));
typedef float f32x4 __attribute__((ext_vector_type(4)));

static __device__ __forceinline__ unsigned short f2bf(float f) {
    unsigned u = __float_as_uint(f);
    unsigned r = (u + 0x7fff + ((u >> 16) & 1)) >> 16;  // RNE
    return (unsigned short)r;
}
static __device__ __forceinline__ float bf2f(unsigned short u) {
    return __uint_as_float((unsigned)u << 16);
}

// ---------------- CSR build ----------------
__global__ void count_kernel(const int* __restrict__ dst, int* __restrict__ cnt, int e) {
    int i = blockIdx.x * blockDim.x + threadIdx.x;
    if (i < e) atomicAdd(&cnt[dst[i]], 1);
}

__global__ __launch_bounds__(256) void bsum_kernel(const int* __restrict__ cnt,
                                                   int* __restrict__ bsum, int n) {
    int i = blockIdx.x * 256 + threadIdx.x;
    int v = (i < n) ? cnt[i] : 0;
    for (int off = 32; off; off >>= 1) v += __shfl_down(v, off, 64);
    __shared__ int sh[4];
    if ((threadIdx.x & 63) == 0) sh[threadIdx.x >> 6] = v;
    __syncthreads();
    if (threadIdx.x == 0) bsum[blockIdx.x] = sh[0] + sh[1] + sh[2] + sh[3];
}

__global__ __launch_bounds__(1024) void bscan_kernel(int* __restrict__ bsum, int nb) {
    __shared__ int sh[1024];
    int t = threadIdx.x;
    int v = (t < nb) ? bsum[t] : 0;
    sh[t] = v;
    __syncthreads();
    for (int off = 1; off < 1024; off <<= 1) {
        int u = (t >= off) ? sh[t - off] : 0;
        __syncthreads();
        sh[t] += u;
        __syncthreads();
    }
    if (t < nb) bsum[t] = sh[t] - v;  // exclusive
}

__global__ __launch_bounds__(256) void scanw_kernel(const int* __restrict__ cnt,
                                                    const int* __restrict__ boff,
                                                    int* __restrict__ row_ptr,
                                                    int* __restrict__ fill,
                                                    float* __restrict__ dinv, int n) {
    __shared__ int sh[256];
    int t = threadIdx.x;
    int i = blockIdx.x * 256 + t;
    int v = (i < n) ? cnt[i] : 0;
    sh[t] = v;
    __syncthreads();
    for (int off = 1; off < 256; off <<= 1) {
        int u = (t >= off) ? sh[t - off] : 0;
        __syncthreads();
        sh[t] += u;
        __syncthreads();
    }
    int excl = boff[blockIdx.x] + sh[t] - v;
    if (i < n) {
        row_ptr[i] = excl;
        fill[i] = excl;
        dinv[i] = rsqrtf((float)v + 1.0f);
        if (i == n - 1) row_ptr[n] = excl + v;
    }
}

__global__ void bucket_kernel(const int* __restrict__ src, const int* __restrict__ dst,
                              int* __restrict__ fill, int* __restrict__ esrc, int e) {
    int i = blockIdx.x * blockDim.x + threadIdx.x;
    if (i < e) {
        int pos = atomicAdd(&fill[dst[i]], 1);
        esrc[pos] = src[i];
    }
}

// ---------------- weight pack ----------------
// pack W[K,N] f32 -> Bp bf16 fragment layout: [(kt*N/16+ct)*64+lane][8]
__global__ void pack_b_kernel(const float* __restrict__ W, ushort* __restrict__ Bp,
                              int K, int N) {
    int tid = blockIdx.x * blockDim.x + threadIdx.x;
    if (tid >= K * N) return;
    int j = tid & 7;
    int lane = (tid >> 3) & 63;
    int rest = tid >> 9;
    int nct = N >> 4;
    int ct = rest % nct, kt = rest / nct;
    int k = kt * 32 + (lane >> 4) * 8 + j;
    int col = ct * 16 + (lane & 15);
    Bp[tid] = f2bf(W[(size_t)k * N + col]);
}

// ---------------- MFMA GEMM ----------------
// block = 256 thr (4 waves); wave computes 32 rows x NCT*16 cols
// ACT: 0 plain->f32, 1 relu->bf16, 2 sigmoid->f32, 3 plain->bf16
// AF32: A is f32 (convert in-kernel) else bf16
template<int K, int NCT, int ACT, int AF32>
__global__ __launch_bounds__(256) void mfma_gemm(
    const void* __restrict__ A, const ushort* __restrict__ Bp,
    const float* __restrict__ bias, void* __restrict__ Cout,
    int M, int ldc, int totct) {
    const int tid = threadIdx.x;
    const int wid = tid >> 6, lane = tid & 63;
    const int ct0 = blockIdx.y * NCT;
    const int rowbase = blockIdx.x * 128 + wid * 32;
    const int ak = (lane >> 4) * 8;

    f32x4 acc[2][NCT];
#pragma unroll
    for (int s = 0; s < 2; s++)
#pragma unroll
        for (int c = 0; c < NCT; c++) acc[s][c] = (f32x4){0.f, 0.f, 0.f, 0.f};

    int r0 = rowbase + (lane & 15); if (r0 >= M) r0 = M - 1;
    int r1 = rowbase + 16 + (lane & 15); if (r1 >= M) r1 = M - 1;
    const float*  a0f = (const float*)A + (size_t)r0 * K + ak;
    const float*  a1f = (const float*)A + (size_t)r1 * K + ak;
    const ushort* a0b = (const ushort*)A + (size_t)r0 * K + ak;
    const ushort* a1b = (const ushort*)A + (size_t)r1 * K + ak;

#pragma unroll
    for (int kt = 0; kt < K / 32; kt++) {
        bf16x8 a0, a1;
        if (AF32) {
            float u[8], v[8];
            *(float4*)u = *(const float4*)(a0f + kt * 32);
            *(float4*)(u + 4) = *(const float4*)(a0f + kt * 32 + 4);
            *(float4*)v = *(const float4*)(a1f + kt * 32);
            *(float4*)(v + 4) = *(const float4*)(a1f + kt * 32 + 4);
#pragma unroll
            for (int j = 0; j < 8; j++) { a0[j] = (short)f2bf(u[j]); a1[j] = (short)f2bf(v[j]); }
        } else {
            a0 = *reinterpret_cast<const bf16x8*>(a0b + kt * 32);
            a1 = *reinterpret_cast<const bf16x8*>(a1b + kt * 32);
        }
        const ushort* bp = Bp + ((size_t)(kt * totct + ct0) * 64 + lane) * 8;
#pragma unroll
        for (int c = 0; c < NCT; c++) {
            bf16x8 b = *reinterpret_cast<const bf16x8*>(bp + (size_t)c * 64 * 8);
            acc[0][c] = __builtin_amdgcn_mfma_f32_16x16x32_bf16(a0, b, acc[0][c], 0, 0, 0);
            acc[1][c] = __builtin_amdgcn_mfma_f32_16x16x32_bf16(a1, b, acc[1][c], 0, 0, 0);
        }
    }

    const int ccol = lane & 15;
    const int crow = (lane >> 4) * 4;
#pragma unroll
    for (int s = 0; s < 2; s++) {
#pragma unroll
        for (int c = 0; c < NCT; c++) {
            int col = (ct0 + c) * 16 + ccol;
            float bb = bias ? bias[col] : 0.f;
#pragma unroll
            for (int r = 0; r < 4; r++) {
                int row = rowbase + s * 16 + crow + r;
                if (row >= M) continue;
                float v = acc[s][c][r] + bb;
                if (ACT == 1) {
                    v = v > 0.f ? v : 0.f;
                    ((ushort*)Cout)[(size_t)row * ldc + col] = f2bf(v);
                } else if (ACT == 2) {
                    v = 1.f / (1.f + __expf(-v));
                    ((float*)Cout)[(size_t)row * ldc + col] = v;
                } else if (ACT == 3) {
                    ((ushort*)Cout)[(size_t)row * ldc + col] = f2bf(v);
                } else {
                    ((float*)Cout)[(size_t)row * ldc + col] = v;
                }
            }
        }
    }
}

// ---------------- CSR gather (bf16 h) + fused p/q ----------------
// 8 nodes per 256-thread block; 32 threads/node, 4 features (8B bf16) per thread
__global__ __launch_bounds__(256) void gather_pq_kernel(
    const ushort* __restrict__ h, const int* __restrict__ row_ptr,
    const int* __restrict__ esrc, const float* __restrict__ dinv,
    const float* __restrict__ bg, const float* __restrict__ Wa,
    ushort* __restrict__ outb, float* __restrict__ p, float* __restrict__ q, int n) {
    int tid = threadIdx.x;
    int node = blockIdx.x * 8 + (tid >> 5);
    int c4 = (tid & 31) * 4;
    if (node >= n) return;
    float di = dinv[node];
    int r0 = row_ptr[node], r1 = row_ptr[node + 1];
    ushort4 hv = *(const ushort4*)(h + (size_t)node * HFEAT + c4);
    float4 acc = make_float4(bf2f(hv.x) * di, bf2f(hv.y) * di,
                             bf2f(hv.z) * di, bf2f(hv.w) * di);
    int e = r0;
    for (; e + 1 < r1; e += 2) {
        int s0 = esrc[e], s1 = esrc[e + 1];
        float d0 = dinv[s0], d1 = dinv[s1];
        ushort4 v0 = *(const ushort4*)(h + (size_t)s0 * HFEAT + c4);
        ushort4 v1 = *(const ushort4*)(h + (size_t)s1 * HFEAT + c4);
        acc.x = fmaf(bf2f(v0.x), d0, acc.x); acc.y = fmaf(bf2f(v0.y), d0, acc.y);
        acc.z = fmaf(bf2f(v0.z), d0, acc.z); acc.w = fmaf(bf2f(v0.w), d0, acc.w);
        acc.x = fmaf(bf2f(v1.x), d1, acc.x); acc.y = fmaf(bf2f(v1.y), d1, acc.y);
        acc.z = fmaf(bf2f(v1.z), d1, acc.z); acc.w = fmaf(bf2f(v1.w), d1, acc.w);
    }
    if (e < r1) {
        int s0 = esrc[e];
        float d0 = dinv[s0];
        ushort4 v0 = *(const ushort4*)(h + (size_t)s0 * HFEAT + c4);
        acc.x = fmaf(bf2f(v0.x), d0, acc.x); acc.y = fmaf(bf2f(v0.y), d0, acc.y);
        acc.z = fmaf(bf2f(v0.z), d0, acc.z); acc.w = fmaf(bf2f(v0.w), d0, acc.w);
    }
    float4 bb = *(const float4*)(bg + c4);
    float ox = fmaf(acc.x, di, bb.x);
    float oy = fmaf(acc.y, di, bb.y);
    float oz = fmaf(acc.z, di, bb.z);
    float ow = fmaf(acc.w, di, bb.w);
    ushort4 o;
    o.x = f2bf(ox); o.y = f2bf(oy); o.z = f2bf(oz); o.w = f2bf(ow);
    *(ushort4*)(outb + (size_t)node * HFEAT + c4) = o;

    // fused p/q: p = out·Wa[0:128], q = out·Wa[128:256] (f32 values, pre-rounding)
    float4 wp = *(const float4*)(Wa + c4);
    float4 wq = *(const float4*)(Wa + HFEAT + c4);
    float pp = ox * wp.x + oy * wp.y + oz * wp.z + ow * wp.w;
    float qq = ox * wq.x + oy * wq.y + oz * wq.z + ow * wq.w;
    for (int off = 16; off; off >>= 1) {
        pp += __shfl_down(pp, off, 32);
        qq += __shfl_down(qq, off, 32);
    }
    if ((tid & 31) == 0) { p[node] = pp; q[node] = qq; }
}

// ---------------- adjacency scores ----------------
__global__ void adj_kernel(const int* __restrict__ k0, const int* __restrict__ k1,
                           const int2* __restrict__ na, const float* __restrict__ p,
                           const float* __restrict__ q, const float* __restrict__ ba,
                           float* __restrict__ outp, int ek, int en) {
    int e = blockIdx.x * blockDim.x + threadIdx.x;
    int tot = ek + en;
    if (e >= tot) return;
    int a, b;
    if (e < ek) { a = k0[e]; b = k1[e]; }
    else { int2 ab = na[e - ek]; a = ab.x; b = ab.y; }
    float v = p[a] + q[b] + ba[0];
    outp[e] = 1.f / (1.f + __expf(-v));
}

extern "C" void kernel_launch(void* const* d_in, const int* in_sizes, int n_in,
                              void* d_out, int out_size, void* d_ws, size_t ws_size,
                              hipStream_t stream) {
    const float* x  = (const float*)d_in[0];
    const int*   ei = (const int*)d_in[1];
    const int*   kh = (const int*)d_in[2];
    const int*   na = (const int*)d_in[3];
    const float* Wg = (const float*)d_in[4];
    const float* bg = (const float*)d_in[5];
    const float* W1 = (const float*)d_in[6];
    const float* b1 = (const float*)d_in[7];
    const float* W2 = (const float*)d_in[8];
    const float* b2 = (const float*)d_in[9];
    const float* Wa = (const float*)d_in[10];
    const float* ba = (const float*)d_in[11];

    const int N  = in_sizes[0] / FFEAT;
    const int E  = in_sizes[1] / 2;
    const int EK = in_sizes[2] / 2;
    const int EN = in_sizes[3] / 2;

    float* fo = (float*)d_out;             // feature_out [N, 256] f32
    float* ao = fo + (size_t)N * FFEAT;    // adj_out [EK+EN]

    char* ws = (char*)d_ws;
    ushort* h    = (ushort*)ws;  ws += (size_t)N * HFEAT * 2;   // 12.8 MB (bf16)
    ushort* outb = (ushort*)ws;  ws += (size_t)N * HFEAT * 2;   // 12.8 MB
    ushort* zb   = (ushort*)ws;  ws += (size_t)N * HFEAT * 2;   // 12.8 MB
    ushort* WgP  = (ushort*)ws;  ws += (size_t)FFEAT * HFEAT * 2;
    ushort* W1P  = (ushort*)ws;  ws += (size_t)HFEAT * HFEAT * 2;
    ushort* W2P  = (ushort*)ws;  ws += (size_t)HFEAT * FFEAT * 2;
    float*  dinv = (float*)ws;   ws += (size_t)N * 4;
    float*  p    = (float*)ws;   ws += (size_t)N * 4;
    float*  q    = (float*)ws;   ws += (size_t)N * 4;
    int*    cnt  = (int*)ws;     ws += (size_t)N * 4;
    int*    row_ptr = (int*)ws;  ws += (size_t)(N + 1) * 4;
    int*    fill = (int*)ws;     ws += (size_t)N * 4;
    int*    bsum = (int*)ws;     ws += (size_t)1024 * 4;
    int*    esrc = (int*)ws;     ws += (size_t)E * 4;

    const int B = 256;
    const int NB = (N + 255) / 256;
    const int GX = (N + 127) / 128;

    // CSR build
    hipMemsetAsync(cnt, 0, (size_t)N * 4, stream);
    count_kernel<<<(E + B - 1) / B, B, 0, stream>>>(ei + E, cnt, E);
    bsum_kernel<<<NB, B, 0, stream>>>(cnt, bsum, N);
    bscan_kernel<<<1, 1024, 0, stream>>>(bsum, NB);
    scanw_kernel<<<NB, B, 0, stream>>>(cnt, bsum, row_ptr, fill, dinv, N);
    bucket_kernel<<<(E + B - 1) / B, B, 0, stream>>>(ei, ei + E, fill, esrc, E);

    // weight packs
    pack_b_kernel<<<(FFEAT * HFEAT + B - 1) / B, B, 0, stream>>>(Wg, WgP, FFEAT, HFEAT);
    pack_b_kernel<<<(HFEAT * HFEAT + B - 1) / B, B, 0, stream>>>(W1, W1P, HFEAT, HFEAT);
    pack_b_kernel<<<(HFEAT * FFEAT + B - 1) / B, B, 0, stream>>>(W2, W2P, HFEAT, FFEAT);

    // G1: h = bf16( x(f32) @ Wg )  -> bf16, in-kernel A convert, single pass
    mfma_gemm<FFEAT, 8, 3, 1><<<dim3(GX, 1), B, 0, stream>>>(x, WgP, nullptr, h, N, HFEAT, HFEAT / 16);

    // GCN aggregate -> outb (bf16), bias fused, p/q fused
    gather_pq_kernel<<<(N + 7) / 8, B, 0, stream>>>(h, row_ptr, esrc, dinv, bg, Wa, outb, p, q, N);

    // G2: zb = relu(outb @ W1 + b1) -> bf16
    mfma_gemm<HFEAT, 8, 1, 0><<<dim3(GX, 1), B, 0, stream>>>(outb, W1P, b1, zb, N, HFEAT, HFEAT / 16);

    // G3: fo = sigmoid(zb @ W2 + b2) -> f32
    mfma_gemm<HFEAT, 8, 2, 0><<<dim3(GX, 2), B, 0, stream>>>(zb, W2P, b2, fo, N, FFEAT, FFEAT / 16);

    // adjacency scores
    adj_kernel<<<(EK + EN + B - 1) / B, B, 0, stream>>>(kh, kh + EK, (const int2*)na, p, q, ba, ao, EK, EN);
}

// Round 7
// 210.484 us; speedup vs baseline: 7.6169x; 1.0787x over previous
//
#include <hip/hip_runtime.h>
#include <cstdint>
#include <cstddef>

#define HFEAT 128
#define FFEAT 256

typedef short bf16x8 __attribute__((ext_vector_type(8)));
typedef float f32x4 __attribute__((ext_vector_type(4)));
typedef unsigned short ushort8v __attribute__((ext_vector_type(8)));

static __device__ __forceinline__ unsigned short f2bf(float f) {
    unsigned u = __float_as_uint(f);
    unsigned r = (u + 0x7fff + ((u >> 16) & 1)) >> 16;  // RNE
    return (unsigned short)r;
}
static __device__ __forceinline__ float bf2f(unsigned short u) {
    return __uint_as_float((unsigned)u << 16);
}

// ---------------- CSR build ----------------
__global__ void count_kernel(const int* __restrict__ dst, int* __restrict__ cnt, int e) {
    int i = blockIdx.x * blockDim.x + threadIdx.x;
    if (i < e) atomicAdd(&cnt[dst[i]], 1);
}

__global__ __launch_bounds__(256) void bsum_kernel(const int* __restrict__ cnt,
                                                   int* __restrict__ bsum, int n) {
    int i = blockIdx.x * 256 + threadIdx.x;
    int v = (i < n) ? cnt[i] : 0;
    for (int off = 32; off; off >>= 1) v += __shfl_down(v, off, 64);
    __shared__ int sh[4];
    if ((threadIdx.x & 63) == 0) sh[threadIdx.x >> 6] = v;
    __syncthreads();
    if (threadIdx.x == 0) bsum[blockIdx.x] = sh[0] + sh[1] + sh[2] + sh[3];
}

__global__ __launch_bounds__(1024) void bscan_kernel(int* __restrict__ bsum, int nb) {
    __shared__ int sh[1024];
    int t = threadIdx.x;
    int v = (t < nb) ? bsum[t] : 0;
    sh[t] = v;
    __syncthreads();
    for (int off = 1; off < 1024; off <<= 1) {
        int u = (t >= off) ? sh[t - off] : 0;
        __syncthreads();
        sh[t] += u;
        __syncthreads();
    }
    if (t < nb) bsum[t] = sh[t] - v;  // exclusive
}

__global__ __launch_bounds__(256) void scanw_kernel(const int* __restrict__ cnt,
                                                    const int* __restrict__ boff,
                                                    int* __restrict__ row_ptr,
                                                    int* __restrict__ fill,
                                                    float* __restrict__ dinv, int n) {
    __shared__ int sh[256];
    int t = threadIdx.x;
    int i = blockIdx.x * 256 + t;
    int v = (i < n) ? cnt[i] : 0;
    sh[t] = v;
    __syncthreads();
    for (int off = 1; off < 256; off <<= 1) {
        int u = (t >= off) ? sh[t - off] : 0;
        __syncthreads();
        sh[t] += u;
        __syncthreads();
    }
    int excl = boff[blockIdx.x] + sh[t] - v;
    if (i < n) {
        row_ptr[i] = excl;
        fill[i] = excl;
        dinv[i] = rsqrtf((float)v + 1.0f);
        if (i == n - 1) row_ptr[n] = excl + v;
    }
}

__global__ void bucket_kernel(const int* __restrict__ src, const int* __restrict__ dst,
                              int* __restrict__ fill, ushort* __restrict__ esrc, int e) {
    int i = blockIdx.x * blockDim.x + threadIdx.x;
    if (i < e) {
        int pos = atomicAdd(&fill[dst[i]], 1);
        esrc[pos] = (ushort)src[i];
    }
}

// ---------------- fused weight pack (Wg, W1, W2 in one launch) ----------------
// layout per GEMM: Bp[((kt*(N/16)+ct)*64+lane)*8 + j] = bf16(W[kt*32+8*(lane>>4)+j][ct*16+(lane&15)])
static __device__ __forceinline__ void pack_one(const float* __restrict__ W,
                                                ushort* __restrict__ Bp,
                                                int tid, int N) {
    int j = tid & 7;
    int lane = (tid >> 3) & 63;
    int rest = tid >> 9;
    int nct = N >> 4;
    int ct = rest % nct, kt = rest / nct;
    int k = kt * 32 + (lane >> 4) * 8 + j;
    int col = ct * 16 + (lane & 15);
    Bp[tid] = f2bf(W[(size_t)k * N + col]);
}

__global__ void pack_all_kernel(const float* __restrict__ Wg, const float* __restrict__ W1,
                                const float* __restrict__ W2, ushort* __restrict__ WgP,
                                ushort* __restrict__ W1P, ushort* __restrict__ W2P) {
    int tid = blockIdx.x * 256 + threadIdx.x;
    if (tid < FFEAT * HFEAT) {
        pack_one(Wg, WgP, tid, HFEAT);
    } else if (tid < FFEAT * HFEAT + HFEAT * HFEAT) {
        pack_one(W1, W1P, tid - FFEAT * HFEAT, HFEAT);
    } else if (tid < FFEAT * HFEAT + HFEAT * HFEAT + HFEAT * FFEAT) {
        pack_one(W2, W2P, tid - FFEAT * HFEAT - HFEAT * HFEAT, FFEAT);
    }
}

// ---------------- MFMA GEMM ----------------
// block = 256 thr (4 waves); wave computes 32 rows x NCT*16 cols
// ACT: 0 plain->f32, 1 relu->bf16, 2 sigmoid->f32, 3 plain->bf16
// AF32: A is f32 (convert in-kernel) else bf16
template<int K, int NCT, int ACT, int AF32>
__global__ __launch_bounds__(256) void mfma_gemm(
    const void* __restrict__ A, const ushort* __restrict__ Bp,
    const float* __restrict__ bias, void* __restrict__ Cout,
    int M, int ldc, int totct) {
    const int tid = threadIdx.x;
    const int wid = tid >> 6, lane = tid & 63;
    const int ct0 = blockIdx.y * NCT;
    const int rowbase = blockIdx.x * 128 + wid * 32;
    const int ak = (lane >> 4) * 8;

    f32x4 acc[2][NCT];
#pragma unroll
    for (int s = 0; s < 2; s++)
#pragma unroll
        for (int c = 0; c < NCT; c++) acc[s][c] = (f32x4){0.f, 0.f, 0.f, 0.f};

    int r0 = rowbase + (lane & 15); if (r0 >= M) r0 = M - 1;
    int r1 = rowbase + 16 + (lane & 15); if (r1 >= M) r1 = M - 1;
    const float*  a0f = (const float*)A + (size_t)r0 * K + ak;
    const float*  a1f = (const float*)A + (size_t)r1 * K + ak;
    const ushort* a0b = (const ushort*)A + (size_t)r0 * K + ak;
    const ushort* a1b = (const ushort*)A + (size_t)r1 * K + ak;

#pragma unroll
    for (int kt = 0; kt < K / 32; kt++) {
        bf16x8 a0, a1;
        if (AF32) {
            float u[8], v[8];
            *(float4*)u = *(const float4*)(a0f + kt * 32);
            *(float4*)(u + 4) = *(const float4*)(a0f + kt * 32 + 4);
            *(float4*)v = *(const float4*)(a1f + kt * 32);
            *(float4*)(v + 4) = *(const float4*)(a1f + kt * 32 + 4);
#pragma unroll
            for (int j = 0; j < 8; j++) { a0[j] = (short)f2bf(u[j]); a1[j] = (short)f2bf(v[j]); }
        } else {
            a0 = *reinterpret_cast<const bf16x8*>(a0b + kt * 32);
            a1 = *reinterpret_cast<const bf16x8*>(a1b + kt * 32);
        }
        const ushort* bp = Bp + ((size_t)(kt * totct + ct0) * 64 + lane) * 8;
#pragma unroll
        for (int c = 0; c < NCT; c++) {
            bf16x8 b = *reinterpret_cast<const bf16x8*>(bp + (size_t)c * 64 * 8);
            acc[0][c] = __builtin_amdgcn_mfma_f32_16x16x32_bf16(a0, b, acc[0][c], 0, 0, 0);
            acc[1][c] = __builtin_amdgcn_mfma_f32_16x16x32_bf16(a1, b, acc[1][c], 0, 0, 0);
        }
    }

    const int ccol = lane & 15;
    const int crow = (lane >> 4) * 4;
#pragma unroll
    for (int s = 0; s < 2; s++) {
#pragma unroll
        for (int c = 0; c < NCT; c++) {
            int col = (ct0 + c) * 16 + ccol;
            float bb = bias ? bias[col] : 0.f;
#pragma unroll
            for (int r = 0; r < 4; r++) {
                int row = rowbase + s * 16 + crow + r;
                if (row >= M) continue;
                float v = acc[s][c][r] + bb;
                if (ACT == 1) {
                    v = v > 0.f ? v : 0.f;
                    ((ushort*)Cout)[(size_t)row * ldc + col] = f2bf(v);
                } else if (ACT == 2) {
                    v = 1.f / (1.f + __expf(-v));
                    ((float*)Cout)[(size_t)row * ldc + col] = v;
                } else if (ACT == 3) {
                    ((ushort*)Cout)[(size_t)row * ldc + col] = f2bf(v);
                } else {
                    ((float*)Cout)[(size_t)row * ldc + col] = v;
                }
            }
        }
    }
}

// ---------------- CSR gather (bf16 h, ushort esrc) + fused p/q ----------------
// 16 nodes per 256-thread block; 16 threads/node, 8 features (16B bf16) per thread
__global__ __launch_bounds__(256) void gather_pq_kernel(
    const ushort* __restrict__ h, const int* __restrict__ row_ptr,
    const ushort* __restrict__ esrc, const float* __restrict__ dinv,
    const float* __restrict__ bg, const float* __restrict__ Wa,
    ushort* __restrict__ outb, float* __restrict__ p, float* __restrict__ q, int n) {
    int tid = threadIdx.x;
    int node = blockIdx.x * 16 + (tid >> 4);
    int c8 = (tid & 15) * 8;
    if (node >= n) return;
    float di = dinv[node];
    int r0 = row_ptr[node], r1 = row_ptr[node + 1];
    float acc[8];
    {
        ushort8v hv = *(const ushort8v*)(h + (size_t)node * HFEAT + c8);
#pragma unroll
        for (int j = 0; j < 8; j++) acc[j] = bf2f(hv[j]) * di;
    }
    int e = r0;
    for (; e + 1 < r1; e += 2) {
        int s0 = esrc[e], s1 = esrc[e + 1];
        float d0 = dinv[s0], d1 = dinv[s1];
        ushort8v v0 = *(const ushort8v*)(h + (size_t)s0 * HFEAT + c8);
        ushort8v v1 = *(const ushort8v*)(h + (size_t)s1 * HFEAT + c8);
#pragma unroll
        for (int j = 0; j < 8; j++) acc[j] = fmaf(bf2f(v0[j]), d0, acc[j]);
#pragma unroll
        for (int j = 0; j < 8; j++) acc[j] = fmaf(bf2f(v1[j]), d1, acc[j]);
    }
    if (e < r1) {
        int s0 = esrc[e];
        float d0 = dinv[s0];
        ushort8v v0 = *(const ushort8v*)(h + (size_t)s0 * HFEAT + c8);
#pragma unroll
        for (int j = 0; j < 8; j++) acc[j] = fmaf(bf2f(v0[j]), d0, acc[j]);
    }
    float o[8];
    ushort8v ov;
#pragma unroll
    for (int j = 0; j < 8; j++) {
        o[j] = fmaf(acc[j], di, bg[c8 + j]);
        ov[j] = f2bf(o[j]);
    }
    *(ushort8v*)(outb + (size_t)node * HFEAT + c8) = ov;

    // fused p/q (f32 values pre-rounding)
    float pp = 0.f, qq = 0.f;
#pragma unroll
    for (int j = 0; j < 8; j++) {
        pp = fmaf(o[j], Wa[c8 + j], pp);
        qq = fmaf(o[j], Wa[HFEAT + c8 + j], qq);
    }
    for (int off = 8; off; off >>= 1) {
        pp += __shfl_down(pp, off, 16);
        qq += __shfl_down(qq, off, 16);
    }
    if ((tid & 15) == 0) { p[node] = pp; q[node] = qq; }
}

// ---------------- adjacency scores ----------------
__global__ void adj_kernel(const int* __restrict__ k0, const int* __restrict__ k1,
                           const int2* __restrict__ na, const float* __restrict__ p,
                           const float* __restrict__ q, const float* __restrict__ ba,
                           float* __restrict__ outp, int ek, int en) {
    int e = blockIdx.x * blockDim.x + threadIdx.x;
    int tot = ek + en;
    if (e >= tot) return;
    int a, b;
    if (e < ek) { a = k0[e]; b = k1[e]; }
    else { int2 ab = na[e - ek]; a = ab.x; b = ab.y; }
    float v = p[a] + q[b] + ba[0];
    outp[e] = 1.f / (1.f + __expf(-v));
}

extern "C" void kernel_launch(void* const* d_in, const int* in_sizes, int n_in,
                              void* d_out, int out_size, void* d_ws, size_t ws_size,
                              hipStream_t stream) {
    const float* x  = (const float*)d_in[0];
    const int*   ei = (const int*)d_in[1];
    const int*   kh = (const int*)d_in[2];
    const int*   na = (const int*)d_in[3];
    const float* Wg = (const float*)d_in[4];
    const float* bg = (const float*)d_in[5];
    const float* W1 = (const float*)d_in[6];
    const float* b1 = (const float*)d_in[7];
    const float* W2 = (const float*)d_in[8];
    const float* b2 = (const float*)d_in[9];
    const float* Wa = (const float*)d_in[10];
    const float* ba = (const float*)d_in[11];

    const int N  = in_sizes[0] / FFEAT;
    const int E  = in_sizes[1] / 2;
    const int EK = in_sizes[2] / 2;
    const int EN = in_sizes[3] / 2;

    float* fo = (float*)d_out;             // feature_out [N, 256] f32
    float* ao = fo + (size_t)N * FFEAT;    // adj_out [EK+EN]

    char* ws = (char*)d_ws;
    ushort* h    = (ushort*)ws;  ws += (size_t)N * HFEAT * 2;   // bf16
    ushort* outb = (ushort*)ws;  ws += (size_t)N * HFEAT * 2;
    ushort* zb   = (ushort*)ws;  ws += (size_t)N * HFEAT * 2;
    ushort* WgP  = (ushort*)ws;  ws += (size_t)FFEAT * HFEAT * 2;
    ushort* W1P  = (ushort*)ws;  ws += (size_t)HFEAT * HFEAT * 2;
    ushort* W2P  = (ushort*)ws;  ws += (size_t)HFEAT * FFEAT * 2;
    float*  dinv = (float*)ws;   ws += (size_t)N * 4;
    float*  p    = (float*)ws;   ws += (size_t)N * 4;
    float*  q    = (float*)ws;   ws += (size_t)N * 4;
    int*    cnt  = (int*)ws;     ws += (size_t)N * 4;
    int*    row_ptr = (int*)ws;  ws += (size_t)(N + 1) * 4;
    int*    fill = (int*)ws;     ws += (size_t)N * 4;
    int*    bsum = (int*)ws;     ws += (size_t)1024 * 4;
    ushort* esrc = (ushort*)ws;  ws += (size_t)E * 2;

    const int B = 256;
    const int NB = (N + 255) / 256;
    const int GX = (N + 127) / 128;

    // CSR build
    hipMemsetAsync(cnt, 0, (size_t)N * 4, stream);
    count_kernel<<<(E + B - 1) / B, B, 0, stream>>>(ei + E, cnt, E);
    bsum_kernel<<<NB, B, 0, stream>>>(cnt, bsum, N);
    bscan_kernel<<<1, 1024, 0, stream>>>(bsum, NB);
    scanw_kernel<<<NB, B, 0, stream>>>(cnt, bsum, row_ptr, fill, dinv, N);
    bucket_kernel<<<(E + B - 1) / B, B, 0, stream>>>(ei, ei + E, fill, esrc, E);

    // fused weight packs (one launch)
    pack_all_kernel<<<(FFEAT * HFEAT + HFEAT * HFEAT + HFEAT * FFEAT + B - 1) / B, B, 0, stream>>>(
        Wg, W1, W2, WgP, W1P, W2P);

    // G1: h = bf16( x(f32) @ Wg ), in-kernel A convert, single pass
    mfma_gemm<FFEAT, 8, 3, 1><<<dim3(GX, 1), B, 0, stream>>>(x, WgP, nullptr, h, N, HFEAT, HFEAT / 16);

    // GCN aggregate -> outb (bf16), bias fused, p/q fused
    gather_pq_kernel<<<(N + 15) / 16, B, 0, stream>>>(h, row_ptr, esrc, dinv, bg, Wa, outb, p, q, N);

    // G2: zb = relu(outb @ W1 + b1) -> bf16
    mfma_gemm<HFEAT, 8, 1, 0><<<dim3(GX, 1), B, 0, stream>>>(outb, W1P, b1, zb, N, HFEAT, HFEAT / 16);

    // G3: fo = sigmoid(zb @ W2 + b2) -> f32
    mfma_gemm<HFEAT, 8, 2, 0><<<dim3(GX, 2), B, 0, stream>>>(zb, W2P, b2, fo, N, FFEAT, FFEAT / 16);

    // adjacency scores
    adj_kernel<<<(EK + EN + B - 1) / B, B, 0, stream>>>(kh, kh + EK, (const int2*)na, p, q, ba, ao, EK, EN);
}

// Round 8
// 152.753 us; speedup vs baseline: 10.4957x; 1.3779x over previous
//
#include <hip/hip_runtime.h>
#include <cstdint>
#include <cstddef>

#define HFEAT 128
#define FFEAT 256
#define EPB 2048  // edges per block for hist/scatter passes

typedef short bf16x8 __attribute__((ext_vector_type(8)));
typedef float f32x4 __attribute__((ext_vector_type(4)));
typedef unsigned short ushort8v __attribute__((ext_vector_type(8)));

static __device__ __forceinline__ unsigned short f2bf(float f) {
    unsigned u = __float_as_uint(f);
    unsigned r = (u + 0x7fff + ((u >> 16) & 1)) >> 16;  // RNE
    return (unsigned short)r;
}
static __device__ __forceinline__ float bf2f(unsigned short u) {
    return __uint_as_float((unsigned)u << 16);
}

// ---------------- CSR build: two-level counting sort (LDS atomics only) ----------------
// Pass A: per-block histogram over coarse buckets (dst>>8), transposed write
__global__ __launch_bounds__(256) void histA_kernel(const int* __restrict__ dst,
                                                    int* __restrict__ histT, int E, int NB_C) {
    __shared__ int hist[256];
    hist[threadIdx.x] = 0;
    __syncthreads();
    int b = blockIdx.x;
    int lo = b * EPB, hi = min(E, lo + EPB);
    for (int i = lo + threadIdx.x; i < hi; i += 256)
        atomicAdd(&hist[dst[i] >> 8], 1);
    __syncthreads();
    histT[threadIdx.x * NB_C + b] = hist[threadIdx.x];
}

// generic per-block sum (reused for histT scan)
__global__ __launch_bounds__(256) void bsum_kernel(const int* __restrict__ in,
                                                   int* __restrict__ bsum, int n) {
    int i = blockIdx.x * 256 + threadIdx.x;
    int v = (i < n) ? in[i] : 0;
    for (int off = 32; off; off >>= 1) v += __shfl_down(v, off, 64);
    __shared__ int sh[4];
    if ((threadIdx.x & 63) == 0) sh[threadIdx.x >> 6] = v;
    __syncthreads();
    if (threadIdx.x == 0) bsum[blockIdx.x] = sh[0] + sh[1] + sh[2] + sh[3];
}

__global__ __launch_bounds__(1024) void bscan_kernel(int* __restrict__ bsum, int nb) {
    __shared__ int sh[1024];
    int t = threadIdx.x;
    int v = (t < nb) ? bsum[t] : 0;
    sh[t] = v;
    __syncthreads();
    for (int off = 1; off < 1024; off <<= 1) {
        int u = (t >= off) ? sh[t - off] : 0;
        __syncthreads();
        sh[t] += u;
        __syncthreads();
    }
    if (t < nb) bsum[t] = sh[t] - v;  // exclusive
}

// generic exclusive scan write-back
__global__ __launch_bounds__(256) void escan_kernel(const int* __restrict__ in,
                                                    const int* __restrict__ boff,
                                                    int* __restrict__ out, int n) {
    __shared__ int sh[256];
    int t = threadIdx.x, i = blockIdx.x * 256 + t;
    int v = (i < n) ? in[i] : 0;
    sh[t] = v;
    __syncthreads();
    for (int off = 1; off < 256; off <<= 1) {
        int u = (t >= off) ? sh[t - off] : 0;
        __syncthreads();
        sh[t] += u;
        __syncthreads();
    }
    if (i < n) out[i] = boff[blockIdx.x] + sh[t] - v;
}

// Pass C: coarse scatter of packed (dst<<16)|src into bucket-sorted order
__global__ __launch_bounds__(256) void scatterC_kernel(const int* __restrict__ src,
                                                       const int* __restrict__ dst,
                                                       const int* __restrict__ scanT,
                                                       unsigned* __restrict__ packed,
                                                       int E, int NB_C) {
    __shared__ int base[256];
    __shared__ int fill[256];
    int t = threadIdx.x, b = blockIdx.x;
    base[t] = scanT[t * NB_C + b];
    fill[t] = 0;
    __syncthreads();
    int lo = b * EPB, hi = min(E, lo + EPB);
    for (int i = lo + t; i < hi; i += 256) {
        int d = dst[i], s = src[i];
        int c = d >> 8;
        int pos = base[c] + atomicAdd(&fill[c], 1);
        packed[pos] = ((unsigned)d << 16) | (unsigned)s;
    }
}

// Pass D: per-coarse-bucket fine sort; writes row_ptr, dinv, esrc (contiguous)
__global__ __launch_bounds__(256) void fineD_kernel(const unsigned* __restrict__ packed,
                                                    const int* __restrict__ scanT,
                                                    ushort* __restrict__ esrc,
                                                    int* __restrict__ row_ptr,
                                                    float* __restrict__ dinv,
                                                    int E, int NB_C, int n) {
    __shared__ int cnt[256];
    __shared__ int excl[256];
    int t = threadIdx.x, blk = blockIdx.x;
    int seg0 = scanT[blk * NB_C];
    int seg1 = (blk == 255) ? E : scanT[(blk + 1) * NB_C];
    cnt[t] = 0;
    __syncthreads();
    for (int i = seg0 + t; i < seg1; i += 256)
        atomicAdd(&cnt[(packed[i] >> 16) & 255], 1);
    __syncthreads();
    excl[t] = cnt[t];
    __syncthreads();
    for (int off = 1; off < 256; off <<= 1) {
        int u = (t >= off) ? excl[t - off] : 0;
        __syncthreads();
        excl[t] += u;
        __syncthreads();
    }
    int ex = excl[t] - cnt[t];  // exclusive within bucket
    int node = blk * 256 + t;
    if (node < n) {
        row_ptr[node] = seg0 + ex;
        dinv[node] = rsqrtf((float)cnt[t] + 1.0f);
        if (node == n - 1) row_ptr[n] = seg0 + ex + cnt[t];
    }
    excl[t] = ex;  // becomes fill counter
    __syncthreads();
    for (int i = seg0 + t; i < seg1; i += 256) {
        unsigned pk = packed[i];
        int dl = (pk >> 16) & 255;
        int pos = seg0 + atomicAdd(&excl[dl], 1);
        esrc[pos] = (ushort)(pk & 0xFFFF);
    }
}

// ---------------- fused weight pack ----------------
static __device__ __forceinline__ void pack_one(const float* __restrict__ W,
                                                ushort* __restrict__ Bp,
                                                int tid, int N) {
    int j = tid & 7;
    int lane = (tid >> 3) & 63;
    int rest = tid >> 9;
    int nct = N >> 4;
    int ct = rest % nct, kt = rest / nct;
    int k = kt * 32 + (lane >> 4) * 8 + j;
    int col = ct * 16 + (lane & 15);
    Bp[tid] = f2bf(W[(size_t)k * N + col]);
}

__global__ void pack_all_kernel(const float* __restrict__ Wg, const float* __restrict__ W1,
                                const float* __restrict__ W2, ushort* __restrict__ WgP,
                                ushort* __restrict__ W1P, ushort* __restrict__ W2P) {
    int tid = blockIdx.x * 256 + threadIdx.x;
    if (tid < FFEAT * HFEAT) {
        pack_one(Wg, WgP, tid, HFEAT);
    } else if (tid < FFEAT * HFEAT + HFEAT * HFEAT) {
        pack_one(W1, W1P, tid - FFEAT * HFEAT, HFEAT);
    } else if (tid < FFEAT * HFEAT + HFEAT * HFEAT + HFEAT * FFEAT) {
        pack_one(W2, W2P, tid - FFEAT * HFEAT - HFEAT * HFEAT, FFEAT);
    }
}

// ---------------- MFMA GEMM ----------------
template<int K, int NCT, int ACT, int AF32>
__global__ __launch_bounds__(256) void mfma_gemm(
    const void* __restrict__ A, const ushort* __restrict__ Bp,
    const float* __restrict__ bias, void* __restrict__ Cout,
    int M, int ldc, int totct) {
    const int tid = threadIdx.x;
    const int wid = tid >> 6, lane = tid & 63;
    const int ct0 = blockIdx.y * NCT;
    const int rowbase = blockIdx.x * 128 + wid * 32;
    const int ak = (lane >> 4) * 8;

    f32x4 acc[2][NCT];
#pragma unroll
    for (int s = 0; s < 2; s++)
#pragma unroll
        for (int c = 0; c < NCT; c++) acc[s][c] = (f32x4){0.f, 0.f, 0.f, 0.f};

    int r0 = rowbase + (lane & 15); if (r0 >= M) r0 = M - 1;
    int r1 = rowbase + 16 + (lane & 15); if (r1 >= M) r1 = M - 1;
    const float*  a0f = (const float*)A + (size_t)r0 * K + ak;
    const float*  a1f = (const float*)A + (size_t)r1 * K + ak;
    const ushort* a0b = (const ushort*)A + (size_t)r0 * K + ak;
    const ushort* a1b = (const ushort*)A + (size_t)r1 * K + ak;

#pragma unroll
    for (int kt = 0; kt < K / 32; kt++) {
        bf16x8 a0, a1;
        if (AF32) {
            float u[8], v[8];
            *(float4*)u = *(const float4*)(a0f + kt * 32);
            *(float4*)(u + 4) = *(const float4*)(a0f + kt * 32 + 4);
            *(float4*)v = *(const float4*)(a1f + kt * 32);
            *(float4*)(v + 4) = *(const float4*)(a1f + kt * 32 + 4);
#pragma unroll
            for (int j = 0; j < 8; j++) { a0[j] = (short)f2bf(u[j]); a1[j] = (short)f2bf(v[j]); }
        } else {
            a0 = *reinterpret_cast<const bf16x8*>(a0b + kt * 32);
            a1 = *reinterpret_cast<const bf16x8*>(a1b + kt * 32);
        }
        const ushort* bp = Bp + ((size_t)(kt * totct + ct0) * 64 + lane) * 8;
#pragma unroll
        for (int c = 0; c < NCT; c++) {
            bf16x8 b = *reinterpret_cast<const bf16x8*>(bp + (size_t)c * 64 * 8);
            acc[0][c] = __builtin_amdgcn_mfma_f32_16x16x32_bf16(a0, b, acc[0][c], 0, 0, 0);
            acc[1][c] = __builtin_amdgcn_mfma_f32_16x16x32_bf16(a1, b, acc[1][c], 0, 0, 0);
        }
    }

    const int ccol = lane & 15;
    const int crow = (lane >> 4) * 4;
#pragma unroll
    for (int s = 0; s < 2; s++) {
#pragma unroll
        for (int c = 0; c < NCT; c++) {
            int col = (ct0 + c) * 16 + ccol;
            float bb = bias ? bias[col] : 0.f;
#pragma unroll
            for (int r = 0; r < 4; r++) {
                int row = rowbase + s * 16 + crow + r;
                if (row >= M) continue;
                float v = acc[s][c][r] + bb;
                if (ACT == 1) {
                    v = v > 0.f ? v : 0.f;
                    ((ushort*)Cout)[(size_t)row * ldc + col] = f2bf(v);
                } else if (ACT == 2) {
                    v = 1.f / (1.f + __expf(-v));
                    ((float*)Cout)[(size_t)row * ldc + col] = v;
                } else if (ACT == 3) {
                    ((ushort*)Cout)[(size_t)row * ldc + col] = f2bf(v);
                } else {
                    ((float*)Cout)[(size_t)row * ldc + col] = v;
                }
            }
        }
    }
}

// ---------------- CSR gather (bf16 h, ushort esrc) + fused p/q ----------------
__global__ __launch_bounds__(256) void gather_pq_kernel(
    const ushort* __restrict__ h, const int* __restrict__ row_ptr,
    const ushort* __restrict__ esrc, const float* __restrict__ dinv,
    const float* __restrict__ bg, const float* __restrict__ Wa,
    ushort* __restrict__ outb, float* __restrict__ p, float* __restrict__ q, int n) {
    int tid = threadIdx.x;
    int node = blockIdx.x * 16 + (tid >> 4);
    int c8 = (tid & 15) * 8;
    if (node >= n) return;
    float di = dinv[node];
    int r0 = row_ptr[node], r1 = row_ptr[node + 1];
    float acc[8];
    {
        ushort8v hv = *(const ushort8v*)(h + (size_t)node * HFEAT + c8);
#pragma unroll
        for (int j = 0; j < 8; j++) acc[j] = bf2f(hv[j]) * di;
    }
    int e = r0;
    for (; e + 1 < r1; e += 2) {
        int s0 = esrc[e], s1 = esrc[e + 1];
        float d0 = dinv[s0], d1 = dinv[s1];
        ushort8v v0 = *(const ushort8v*)(h + (size_t)s0 * HFEAT + c8);
        ushort8v v1 = *(const ushort8v*)(h + (size_t)s1 * HFEAT + c8);
#pragma unroll
        for (int j = 0; j < 8; j++) acc[j] = fmaf(bf2f(v0[j]), d0, acc[j]);
#pragma unroll
        for (int j = 0; j < 8; j++) acc[j] = fmaf(bf2f(v1[j]), d1, acc[j]);
    }
    if (e < r1) {
        int s0 = esrc[e];
        float d0 = dinv[s0];
        ushort8v v0 = *(const ushort8v*)(h + (size_t)s0 * HFEAT + c8);
#pragma unroll
        for (int j = 0; j < 8; j++) acc[j] = fmaf(bf2f(v0[j]), d0, acc[j]);
    }
    float o[8];
    ushort8v ov;
#pragma unroll
    for (int j = 0; j < 8; j++) {
        o[j] = fmaf(acc[j], di, bg[c8 + j]);
        ov[j] = f2bf(o[j]);
    }
    *(ushort8v*)(outb + (size_t)node * HFEAT + c8) = ov;

    float pp = 0.f, qq = 0.f;
#pragma unroll
    for (int j = 0; j < 8; j++) {
        pp = fmaf(o[j], Wa[c8 + j], pp);
        qq = fmaf(o[j], Wa[HFEAT + c8 + j], qq);
    }
    for (int off = 8; off; off >>= 1) {
        pp += __shfl_down(pp, off, 16);
        qq += __shfl_down(qq, off, 16);
    }
    if ((tid & 15) == 0) { p[node] = pp; q[node] = qq; }
}

// ---------------- adjacency scores ----------------
__global__ void adj_kernel(const int* __restrict__ k0, const int* __restrict__ k1,
                           const int2* __restrict__ na, const float* __restrict__ p,
                           const float* __restrict__ q, const float* __restrict__ ba,
                           float* __restrict__ outp, int ek, int en) {
    int e = blockIdx.x * blockDim.x + threadIdx.x;
    int tot = ek + en;
    if (e >= tot) return;
    int a, b;
    if (e < ek) { a = k0[e]; b = k1[e]; }
    else { int2 ab = na[e - ek]; a = ab.x; b = ab.y; }
    float v = p[a] + q[b] + ba[0];
    outp[e] = 1.f / (1.f + __expf(-v));
}

extern "C" void kernel_launch(void* const* d_in, const int* in_sizes, int n_in,
                              void* d_out, int out_size, void* d_ws, size_t ws_size,
                              hipStream_t stream) {
    const float* x  = (const float*)d_in[0];
    const int*   ei = (const int*)d_in[1];
    const int*   kh = (const int*)d_in[2];
    const int*   na = (const int*)d_in[3];
    const float* Wg = (const float*)d_in[4];
    const float* bg = (const float*)d_in[5];
    const float* W1 = (const float*)d_in[6];
    const float* b1 = (const float*)d_in[7];
    const float* W2 = (const float*)d_in[8];
    const float* b2 = (const float*)d_in[9];
    const float* Wa = (const float*)d_in[10];
    const float* ba = (const float*)d_in[11];

    const int N  = in_sizes[0] / FFEAT;
    const int E  = in_sizes[1] / 2;
    const int EK = in_sizes[2] / 2;
    const int EN = in_sizes[3] / 2;

    float* fo = (float*)d_out;             // feature_out [N, 256] f32
    float* ao = fo + (size_t)N * FFEAT;    // adj_out [EK+EN]

    const int NB_C = (E + EPB - 1) / EPB;  // coarse-scatter blocks (391)
    const int n2 = 256 * NB_C;             // histT elements

    char* ws = (char*)d_ws;
    ushort* h    = (ushort*)ws;  ws += (size_t)N * HFEAT * 2;   // bf16
    ushort* outb = (ushort*)ws;  ws += (size_t)N * HFEAT * 2;
    ushort* zb   = (ushort*)ws;  ws += (size_t)N * HFEAT * 2;
    ushort* WgP  = (ushort*)ws;  ws += (size_t)FFEAT * HFEAT * 2;
    ushort* W1P  = (ushort*)ws;  ws += (size_t)HFEAT * HFEAT * 2;
    ushort* W2P  = (ushort*)ws;  ws += (size_t)HFEAT * FFEAT * 2;
    float*  dinv = (float*)ws;   ws += (size_t)N * 4;
    float*  p    = (float*)ws;   ws += (size_t)N * 4;
    float*  q    = (float*)ws;   ws += (size_t)N * 4;
    int*    row_ptr = (int*)ws;  ws += (size_t)(N + 1) * 4;
    int*    histT = (int*)ws;    ws += (size_t)n2 * 4;
    int*    scanT = (int*)ws;    ws += (size_t)n2 * 4;
    int*    bsum  = (int*)ws;    ws += (size_t)1024 * 4;
    unsigned* packed = (unsigned*)ws; ws += (size_t)E * 4;
    ushort* esrc = (ushort*)ws;  ws += (size_t)E * 2;

    const int B = 256;
    const int GX = (N + 127) / 128;

    // CSR build via two-level counting sort (no global atomics)
    histA_kernel<<<NB_C, B, 0, stream>>>(ei + E, histT, E, NB_C);
    bsum_kernel<<<NB_C, B, 0, stream>>>(histT, bsum, n2);
    bscan_kernel<<<1, 1024, 0, stream>>>(bsum, NB_C);
    escan_kernel<<<NB_C, B, 0, stream>>>(histT, bsum, scanT, n2);
    scatterC_kernel<<<NB_C, B, 0, stream>>>(ei, ei + E, scanT, packed, E, NB_C);
    fineD_kernel<<<256, B, 0, stream>>>(packed, scanT, esrc, row_ptr, dinv, E, NB_C, N);

    // fused weight packs
    pack_all_kernel<<<(FFEAT * HFEAT + HFEAT * HFEAT + HFEAT * FFEAT + B - 1) / B, B, 0, stream>>>(
        Wg, W1, W2, WgP, W1P, W2P);

    // G1: h = bf16( x(f32) @ Wg ), in-kernel A convert, single pass
    mfma_gemm<FFEAT, 8, 3, 1><<<dim3(GX, 1), B, 0, stream>>>(x, WgP, nullptr, h, N, HFEAT, HFEAT / 16);

    // GCN aggregate -> outb (bf16), bias fused, p/q fused
    gather_pq_kernel<<<(N + 15) / 16, B, 0, stream>>>(h, row_ptr, esrc, dinv, bg, Wa, outb, p, q, N);

    // G2: zb = relu(outb @ W1 + b1) -> bf16
    mfma_gemm<HFEAT, 8, 1, 0><<<dim3(GX, 1), B, 0, stream>>>(outb, W1P, b1, zb, N, HFEAT, HFEAT / 16);

    // G3: fo = sigmoid(zb @ W2 + b2) -> f32
    mfma_gemm<HFEAT, 8, 2, 0><<<dim3(GX, 2), B, 0, stream>>>(zb, W2P, b2, fo, N, FFEAT, FFEAT / 16);

    // adjacency scores
    adj_kernel<<<(EK + EN + B - 1) / B, B, 0, stream>>>(kh, kh + EK, (const int2*)na, p, q, ba, ao, EK, EN);
}

// Round 9
// 140.111 us; speedup vs baseline: 11.4427x; 1.0902x over previous
//
#include <hip/hip_runtime.h>
#include <cstdint>
#include <cstddef>

#define HFEAT 128
#define FFEAT 256
#define EPB 2048  // edges per block for hist/scatter passes

typedef short bf16x8 __attribute__((ext_vector_type(8)));
typedef float f32x4 __attribute__((ext_vector_type(4)));
typedef unsigned short ushort8v __attribute__((ext_vector_type(8)));

static __device__ __forceinline__ unsigned short f2bf(float f) {
    unsigned u = __float_as_uint(f);
    unsigned r = (u + 0x7fff + ((u >> 16) & 1)) >> 16;  // RNE
    return (unsigned short)r;
}
static __device__ __forceinline__ float bf2f(unsigned short u) {
    return __uint_as_float((unsigned)u << 16);
}

// ---------------- CSR build: two-level counting sort (LDS atomics only) ----------------
__global__ __launch_bounds__(256) void histA_kernel(const int* __restrict__ dst,
                                                    int* __restrict__ histT, int E, int NB_C) {
    __shared__ int hist[256];
    hist[threadIdx.x] = 0;
    __syncthreads();
    int b = blockIdx.x;
    int lo = b * EPB, hi = min(E, lo + EPB);
    for (int i = lo + threadIdx.x; i < hi; i += 256)
        atomicAdd(&hist[dst[i] >> 8], 1);
    __syncthreads();
    histT[threadIdx.x * NB_C + b] = hist[threadIdx.x];
}

__global__ __launch_bounds__(256) void bsum_kernel(const int* __restrict__ in,
                                                   int* __restrict__ bsum, int n) {
    int i = blockIdx.x * 256 + threadIdx.x;
    int v = (i < n) ? in[i] : 0;
    for (int off = 32; off; off >>= 1) v += __shfl_down(v, off, 64);
    __shared__ int sh[4];
    if ((threadIdx.x & 63) == 0) sh[threadIdx.x >> 6] = v;
    __syncthreads();
    if (threadIdx.x == 0) bsum[blockIdx.x] = sh[0] + sh[1] + sh[2] + sh[3];
}

__global__ __launch_bounds__(1024) void bscan_kernel(int* __restrict__ bsum, int nb) {
    __shared__ int sh[1024];
    int t = threadIdx.x;
    int v = (t < nb) ? bsum[t] : 0;
    sh[t] = v;
    __syncthreads();
    for (int off = 1; off < 1024; off <<= 1) {
        int u = (t >= off) ? sh[t - off] : 0;
        __syncthreads();
        sh[t] += u;
        __syncthreads();
    }
    if (t < nb) bsum[t] = sh[t] - v;  // exclusive
}

__global__ __launch_bounds__(256) void escan_kernel(const int* __restrict__ in,
                                                    const int* __restrict__ boff,
                                                    int* __restrict__ out, int n) {
    __shared__ int sh[256];
    int t = threadIdx.x, i = blockIdx.x * 256 + t;
    int v = (i < n) ? in[i] : 0;
    sh[t] = v;
    __syncthreads();
    for (int off = 1; off < 256; off <<= 1) {
        int u = (t >= off) ? sh[t - off] : 0;
        __syncthreads();
        sh[t] += u;
        __syncthreads();
    }
    if (i < n) out[i] = boff[blockIdx.x] + sh[t] - v;
}

__global__ __launch_bounds__(256) void scatterC_kernel(const int* __restrict__ src,
                                                       const int* __restrict__ dst,
                                                       const int* __restrict__ scanT,
                                                       unsigned* __restrict__ packed,
                                                       int E, int NB_C) {
    __shared__ int base[256];
    __shared__ int fill[256];
    int t = threadIdx.x, b = blockIdx.x;
    base[t] = scanT[t * NB_C + b];
    fill[t] = 0;
    __syncthreads();
    int lo = b * EPB, hi = min(E, lo + EPB);
    for (int i = lo + t; i < hi; i += 256) {
        int d = dst[i], s = src[i];
        int c = d >> 8;
        int pos = base[c] + atomicAdd(&fill[c], 1);
        packed[pos] = ((unsigned)d << 16) | (unsigned)s;
    }
}

__global__ __launch_bounds__(256) void fineD_kernel(const unsigned* __restrict__ packed,
                                                    const int* __restrict__ scanT,
                                                    ushort* __restrict__ esrc,
                                                    int* __restrict__ row_ptr,
                                                    float* __restrict__ dinv,
                                                    int E, int NB_C, int n) {
    __shared__ int cnt[256];
    __shared__ int excl[256];
    int t = threadIdx.x, blk = blockIdx.x;
    int seg0 = scanT[blk * NB_C];
    int seg1 = (blk == 255) ? E : scanT[(blk + 1) * NB_C];
    cnt[t] = 0;
    __syncthreads();
    for (int i = seg0 + t; i < seg1; i += 256)
        atomicAdd(&cnt[(packed[i] >> 16) & 255], 1);
    __syncthreads();
    excl[t] = cnt[t];
    __syncthreads();
    for (int off = 1; off < 256; off <<= 1) {
        int u = (t >= off) ? excl[t - off] : 0;
        __syncthreads();
        excl[t] += u;
        __syncthreads();
    }
    int ex = excl[t] - cnt[t];  // exclusive within bucket
    int node = blk * 256 + t;
    if (node < n) {
        row_ptr[node] = seg0 + ex;
        dinv[node] = rsqrtf((float)cnt[t] + 1.0f);
        if (node == n - 1) row_ptr[n] = seg0 + ex + cnt[t];
    }
    excl[t] = ex;  // becomes fill counter
    __syncthreads();
    for (int i = seg0 + t; i < seg1; i += 256) {
        unsigned pk = packed[i];
        int dl = (pk >> 16) & 255;
        int pos = seg0 + atomicAdd(&excl[dl], 1);
        esrc[pos] = (ushort)(pk & 0xFFFF);
    }
}

// ---------------- fused weight pack ----------------
static __device__ __forceinline__ void pack_one(const float* __restrict__ W,
                                                ushort* __restrict__ Bp,
                                                int tid, int N) {
    int j = tid & 7;
    int lane = (tid >> 3) & 63;
    int rest = tid >> 9;
    int nct = N >> 4;
    int ct = rest % nct, kt = rest / nct;
    int k = kt * 32 + (lane >> 4) * 8 + j;
    int col = ct * 16 + (lane & 15);
    Bp[tid] = f2bf(W[(size_t)k * N + col]);
}

__global__ void pack_all_kernel(const float* __restrict__ Wg, const float* __restrict__ W1,
                                const float* __restrict__ W2, ushort* __restrict__ WgP,
                                ushort* __restrict__ W1P, ushort* __restrict__ W2P) {
    int tid = blockIdx.x * 256 + threadIdx.x;
    if (tid < FFEAT * HFEAT) {
        pack_one(Wg, WgP, tid, HFEAT);
    } else if (tid < FFEAT * HFEAT + HFEAT * HFEAT) {
        pack_one(W1, W1P, tid - FFEAT * HFEAT, HFEAT);
    } else if (tid < FFEAT * HFEAT + HFEAT * HFEAT + HFEAT * FFEAT) {
        pack_one(W2, W2P, tid - FFEAT * HFEAT - HFEAT * HFEAT, FFEAT);
    }
}

// ---------------- MFMA GEMM with LDS-staged coalesced epilogue ----------------
// block = 256 thr (4 waves); wave computes 32 rows x NCT*16 cols
// ACT: 0 plain->f32, 1 relu->bf16, 2 sigmoid->f32, 3 plain->bf16
// AF32: A is f32 (convert in-kernel) else bf16
template<int K, int NCT, int ACT, int AF32>
__global__ __launch_bounds__(256) void mfma_gemm(
    const void* __restrict__ A, const ushort* __restrict__ Bp,
    const float* __restrict__ bias, void* __restrict__ Cout,
    int M, int ldc, int totct) {
    constexpr int CH = NCT * 16;        // cols handled per block
    constexpr int CSTR = CH + 4;        // LDS row stride (f32): 4*CSTR % 32 == 16 -> 2-way max
    __shared__ float cs[128 * CSTR];

    const int tid = threadIdx.x;
    const int wid = tid >> 6, lane = tid & 63;
    const int ct0 = blockIdx.y * NCT;
    const int rowbase = blockIdx.x * 128 + wid * 32;
    const int ak = (lane >> 4) * 8;

    f32x4 acc[2][NCT];
#pragma unroll
    for (int s = 0; s < 2; s++)
#pragma unroll
        for (int c = 0; c < NCT; c++) acc[s][c] = (f32x4){0.f, 0.f, 0.f, 0.f};

    int r0 = rowbase + (lane & 15); if (r0 >= M) r0 = M - 1;
    int r1 = rowbase + 16 + (lane & 15); if (r1 >= M) r1 = M - 1;
    const float*  a0f = (const float*)A + (size_t)r0 * K + ak;
    const float*  a1f = (const float*)A + (size_t)r1 * K + ak;
    const ushort* a0b = (const ushort*)A + (size_t)r0 * K + ak;
    const ushort* a1b = (const ushort*)A + (size_t)r1 * K + ak;

#pragma unroll
    for (int kt = 0; kt < K / 32; kt++) {
        bf16x8 a0, a1;
        if (AF32) {
            float u[8], v[8];
            *(float4*)u = *(const float4*)(a0f + kt * 32);
            *(float4*)(u + 4) = *(const float4*)(a0f + kt * 32 + 4);
            *(float4*)v = *(const float4*)(a1f + kt * 32);
            *(float4*)(v + 4) = *(const float4*)(a1f + kt * 32 + 4);
#pragma unroll
            for (int j = 0; j < 8; j++) { a0[j] = (short)f2bf(u[j]); a1[j] = (short)f2bf(v[j]); }
        } else {
            a0 = *reinterpret_cast<const bf16x8*>(a0b + kt * 32);
            a1 = *reinterpret_cast<const bf16x8*>(a1b + kt * 32);
        }
        const ushort* bp = Bp + ((size_t)(kt * totct + ct0) * 64 + lane) * 8;
#pragma unroll
        for (int c = 0; c < NCT; c++) {
            bf16x8 b = *reinterpret_cast<const bf16x8*>(bp + (size_t)c * 64 * 8);
            acc[0][c] = __builtin_amdgcn_mfma_f32_16x16x32_bf16(a0, b, acc[0][c], 0, 0, 0);
            acc[1][c] = __builtin_amdgcn_mfma_f32_16x16x32_bf16(a1, b, acc[1][c], 0, 0, 0);
        }
    }

    // stage accumulators to LDS (2-way max bank aliasing with CSTR pad)
    const int ccol = lane & 15;
    const int crow = (lane >> 4) * 4;
#pragma unroll
    for (int s = 0; s < 2; s++) {
#pragma unroll
        for (int c = 0; c < NCT; c++) {
            float* dstp = cs + (size_t)(wid * 32 + s * 16 + crow) * CSTR + c * 16 + ccol;
#pragma unroll
            for (int r = 0; r < 4; r++)
                dstp[(size_t)r * CSTR] = acc[s][c][r];
        }
    }
    __syncthreads();

    // coalesced writeback with bias/activation
    const int rowblk = blockIdx.x * 128;
    const int colbase = ct0 * 16;
    if (ACT == 0 || ACT == 2) {
        // f32 out: float4 chunks
        constexpr int CPR = CH / 4;  // float4 per row
        for (int i = tid; i < 128 * CPR; i += 256) {
            int row = i / CPR, c4 = (i - row * CPR) * 4;
            int grow = rowblk + row;
            if (grow >= M) continue;
            float4 v = *(const float4*)(cs + (size_t)row * CSTR + c4);
            int col = colbase + c4;
            if (bias) {
                float4 bb = *(const float4*)(bias + col);
                v.x += bb.x; v.y += bb.y; v.z += bb.z; v.w += bb.w;
            }
            if (ACT == 2) {
                v.x = 1.f / (1.f + __expf(-v.x));
                v.y = 1.f / (1.f + __expf(-v.y));
                v.z = 1.f / (1.f + __expf(-v.z));
                v.w = 1.f / (1.f + __expf(-v.w));
            }
            *(float4*)((float*)Cout + (size_t)grow * ldc + col) = v;
        }
    } else {
        // bf16 out: ushort8 chunks
        constexpr int CPR = CH / 8;  // ushort8 per row
        for (int i = tid; i < 128 * CPR; i += 256) {
            int row = i / CPR, c8 = (i - row * CPR) * 8;
            int grow = rowblk + row;
            if (grow >= M) continue;
            int col = colbase + c8;
            float v[8];
            *(float4*)v = *(const float4*)(cs + (size_t)row * CSTR + c8);
            *(float4*)(v + 4) = *(const float4*)(cs + (size_t)row * CSTR + c8 + 4);
            ushort8v o;
#pragma unroll
            for (int j = 0; j < 8; j++) {
                float t = v[j] + (bias ? bias[col + j] : 0.f);
                if (ACT == 1) t = t > 0.f ? t : 0.f;
                o[j] = f2bf(t);
            }
            *(ushort8v*)((ushort*)Cout + (size_t)grow * ldc + col) = o;
        }
    }
}

// ---------------- CSR gather (bf16 h, ushort esrc) + fused p/q ----------------
__global__ __launch_bounds__(256) void gather_pq_kernel(
    const ushort* __restrict__ h, const int* __restrict__ row_ptr,
    const ushort* __restrict__ esrc, const float* __restrict__ dinv,
    const float* __restrict__ bg, const float* __restrict__ Wa,
    ushort* __restrict__ outb, float* __restrict__ p, float* __restrict__ q, int n) {
    int tid = threadIdx.x;
    int node = blockIdx.x * 16 + (tid >> 4);
    int c8 = (tid & 15) * 8;
    if (node >= n) return;
    float di = dinv[node];
    int r0 = row_ptr[node], r1 = row_ptr[node + 1];
    float acc[8];
    {
        ushort8v hv = *(const ushort8v*)(h + (size_t)node * HFEAT + c8);
#pragma unroll
        for (int j = 0; j < 8; j++) acc[j] = bf2f(hv[j]) * di;
    }
    int e = r0;
    for (; e + 1 < r1; e += 2) {
        int s0 = esrc[e], s1 = esrc[e + 1];
        float d0 = dinv[s0], d1 = dinv[s1];
        ushort8v v0 = *(const ushort8v*)(h + (size_t)s0 * HFEAT + c8);
        ushort8v v1 = *(const ushort8v*)(h + (size_t)s1 * HFEAT + c8);
#pragma unroll
        for (int j = 0; j < 8; j++) acc[j] = fmaf(bf2f(v0[j]), d0, acc[j]);
#pragma unroll
        for (int j = 0; j < 8; j++) acc[j] = fmaf(bf2f(v1[j]), d1, acc[j]);
    }
    if (e < r1) {
        int s0 = esrc[e];
        float d0 = dinv[s0];
        ushort8v v0 = *(const ushort8v*)(h + (size_t)s0 * HFEAT + c8);
#pragma unroll
        for (int j = 0; j < 8; j++) acc[j] = fmaf(bf2f(v0[j]), d0, acc[j]);
    }
    float o[8];
    ushort8v ov;
#pragma unroll
    for (int j = 0; j < 8; j++) {
        o[j] = fmaf(acc[j], di, bg[c8 + j]);
        ov[j] = f2bf(o[j]);
    }
    *(ushort8v*)(outb + (size_t)node * HFEAT + c8) = ov;

    float pp = 0.f, qq = 0.f;
#pragma unroll
    for (int j = 0; j < 8; j++) {
        pp = fmaf(o[j], Wa[c8 + j], pp);
        qq = fmaf(o[j], Wa[HFEAT + c8 + j], qq);
    }
    for (int off = 8; off; off >>= 1) {
        pp += __shfl_down(pp, off, 16);
        qq += __shfl_down(qq, off, 16);
    }
    if ((tid & 15) == 0) { p[node] = pp; q[node] = qq; }
}

// ---------------- adjacency scores ----------------
__global__ void adj_kernel(const int* __restrict__ k0, const int* __restrict__ k1,
                           const int2* __restrict__ na, const float* __restrict__ p,
                           const float* __restrict__ q, const float* __restrict__ ba,
                           float* __restrict__ outp, int ek, int en) {
    int e = blockIdx.x * blockDim.x + threadIdx.x;
    int tot = ek + en;
    if (e >= tot) return;
    int a, b;
    if (e < ek) { a = k0[e]; b = k1[e]; }
    else { int2 ab = na[e - ek]; a = ab.x; b = ab.y; }
    float v = p[a] + q[b] + ba[0];
    outp[e] = 1.f / (1.f + __expf(-v));
}

extern "C" void kernel_launch(void* const* d_in, const int* in_sizes, int n_in,
                              void* d_out, int out_size, void* d_ws, size_t ws_size,
                              hipStream_t stream) {
    const float* x  = (const float*)d_in[0];
    const int*   ei = (const int*)d_in[1];
    const int*   kh = (const int*)d_in[2];
    const int*   na = (const int*)d_in[3];
    const float* Wg = (const float*)d_in[4];
    const float* bg = (const float*)d_in[5];
    const float* W1 = (const float*)d_in[6];
    const float* b1 = (const float*)d_in[7];
    const float* W2 = (const float*)d_in[8];
    const float* b2 = (const float*)d_in[9];
    const float* Wa = (const float*)d_in[10];
    const float* ba = (const float*)d_in[11];

    const int N  = in_sizes[0] / FFEAT;
    const int E  = in_sizes[1] / 2;
    const int EK = in_sizes[2] / 2;
    const int EN = in_sizes[3] / 2;

    float* fo = (float*)d_out;             // feature_out [N, 256] f32
    float* ao = fo + (size_t)N * FFEAT;    // adj_out [EK+EN]

    const int NB_C = (E + EPB - 1) / EPB;  // coarse-scatter blocks
    const int n2 = 256 * NB_C;             // histT elements

    char* ws = (char*)d_ws;
    ushort* h    = (ushort*)ws;  ws += (size_t)N * HFEAT * 2;   // bf16
    ushort* outb = (ushort*)ws;  ws += (size_t)N * HFEAT * 2;
    ushort* zb   = (ushort*)ws;  ws += (size_t)N * HFEAT * 2;
    ushort* WgP  = (ushort*)ws;  ws += (size_t)FFEAT * HFEAT * 2;
    ushort* W1P  = (ushort*)ws;  ws += (size_t)HFEAT * HFEAT * 2;
    ushort* W2P  = (ushort*)ws;  ws += (size_t)HFEAT * FFEAT * 2;
    float*  dinv = (float*)ws;   ws += (size_t)N * 4;
    float*  p    = (float*)ws;   ws += (size_t)N * 4;
    float*  q    = (float*)ws;   ws += (size_t)N * 4;
    int*    row_ptr = (int*)ws;  ws += (size_t)(N + 1) * 4;
    int*    histT = (int*)ws;    ws += (size_t)n2 * 4;
    int*    scanT = (int*)ws;    ws += (size_t)n2 * 4;
    int*    bsum  = (int*)ws;    ws += (size_t)1024 * 4;
    unsigned* packed = (unsigned*)ws; ws += (size_t)E * 4;
    ushort* esrc = (ushort*)ws;  ws += (size_t)E * 2;

    const int B = 256;
    const int GX = (N + 127) / 128;

    // CSR build via two-level counting sort (no global atomics)
    histA_kernel<<<NB_C, B, 0, stream>>>(ei + E, histT, E, NB_C);
    bsum_kernel<<<NB_C, B, 0, stream>>>(histT, bsum, n2);
    bscan_kernel<<<1, 1024, 0, stream>>>(bsum, NB_C);
    escan_kernel<<<NB_C, B, 0, stream>>>(histT, bsum, scanT, n2);
    scatterC_kernel<<<NB_C, B, 0, stream>>>(ei, ei + E, scanT, packed, E, NB_C);
    fineD_kernel<<<256, B, 0, stream>>>(packed, scanT, esrc, row_ptr, dinv, E, NB_C, N);

    // fused weight packs
    pack_all_kernel<<<(FFEAT * HFEAT + HFEAT * HFEAT + HFEAT * FFEAT + B - 1) / B, B, 0, stream>>>(
        Wg, W1, W2, WgP, W1P, W2P);

    // G1: h = bf16( x(f32) @ Wg ), in-kernel A convert, single pass
    mfma_gemm<FFEAT, 8, 3, 1><<<dim3(GX, 1), B, 0, stream>>>(x, WgP, nullptr, h, N, HFEAT, HFEAT / 16);

    // GCN aggregate -> outb (bf16), bias fused, p/q fused
    gather_pq_kernel<<<(N + 15) / 16, B, 0, stream>>>(h, row_ptr, esrc, dinv, bg, Wa, outb, p, q, N);

    // G2: zb = relu(outb @ W1 + b1) -> bf16
    mfma_gemm<HFEAT, 8, 1, 0><<<dim3(GX, 1), B, 0, stream>>>(outb, W1P, b1, zb, N, HFEAT, HFEAT / 16);

    // G3: fo = sigmoid(zb @ W2 + b2) -> f32
    mfma_gemm<HFEAT, 8, 2, 0><<<dim3(GX, 2), B, 0, stream>>>(zb, W2P, b2, fo, N, FFEAT, FFEAT / 16);

    // adjacency scores
    adj_kernel<<<(EK + EN + B - 1) / B, B, 0, stream>>>(kh, kh + EK, (const int2*)na, p, q, ba, ao, EK, EN);
}